// Round 11
// baseline (818.728 us; speedup 1.0000x reference)
//
#include <hip/hip_runtime.h>
#include <cstdint>

// Problem constants
#define BB 4
#define NN 16384
#define CC 512
#define HH 16
#define DD 32
#define HID 2048
#define MTOT (BB * NN)        // 65536 tokens

typedef __bf16 bf16_t;
typedef __bf16 bf16x8 __attribute__((ext_vector_type(8)));
typedef __bf16 bf16x4 __attribute__((ext_vector_type(4)));
typedef float  f32x4  __attribute__((ext_vector_type(4)));

// ---- async global->LDS 16B ----
__device__ __forceinline__ void gload_lds16(const void* g, void* l) {
  auto gp = reinterpret_cast<const __attribute__((address_space(1))) char*>(
      reinterpret_cast<uintptr_t>(g));
  auto lp = reinterpret_cast<__attribute__((address_space(3))) char*>(
      reinterpret_cast<uintptr_t>(l));
  __builtin_amdgcn_global_load_lds(gp, lp, 16, 0, 0);
}

// ---- fp32 -> bf16 weight convert ----
__global__ __launch_bounds__(256) void cvt_bf16_kernel(const float* __restrict__ src,
                                                       bf16_t* __restrict__ dst) {
  const long i = ((long)blockIdx.x * 256 + threadIdx.x) * 4;
  const f32x4 v = *(const f32x4*)(src + i);
  bf16x4 o;
  o[0] = (bf16_t)v[0]; o[1] = (bf16_t)v[1]; o[2] = (bf16_t)v[2]; o[3] = (bf16_t)v[3];
  *(bf16x4*)(dst + i) = o;
}

// ---- LayerNorm1: one wave per token; lane owns 8 contiguous channels ----
__global__ __launch_bounds__(256) void norm1_kernel(const float* __restrict__ x,
                                                    const float* __restrict__ w,
                                                    const float* __restrict__ bvec,
                                                    bf16_t* __restrict__ h) {
  const int wv = threadIdx.x >> 6, l = threadIdx.x & 63;
  const long tok = (long)blockIdx.x * 4 + wv;
  const int c0 = l * 8;
  const f32x4 a = *(const f32x4*)(x + tok * CC + c0);
  const f32x4 b = *(const f32x4*)(x + tok * CC + c0 + 4);
  float v[8];
#pragma unroll
  for (int i = 0; i < 4; ++i) { v[i] = a[i]; v[4 + i] = b[i]; }
  float s = 0.f, s2 = 0.f;
#pragma unroll
  for (int i = 0; i < 8; ++i) { s += v[i]; s2 += v[i] * v[i]; }
  for (int off = 32; off; off >>= 1) { s += __shfl_xor(s, off); s2 += __shfl_xor(s2, off); }
  const float mean = s * (1.f / CC);
  const float var  = fmaxf(s2 * (1.f / CC) - mean * mean, 0.f);
  const float rstd = rsqrtf(var + 1e-5f);
  const f32x4 w0 = *(const f32x4*)(w + c0), w1 = *(const f32x4*)(w + c0 + 4);
  const f32x4 b0 = *(const f32x4*)(bvec + c0), b1 = *(const f32x4*)(bvec + c0 + 4);
  bf16x8 o;
#pragma unroll
  for (int i = 0; i < 4; ++i) {
    o[i]     = (bf16_t)(w0[i] * (v[i] - mean) * rstd + b0[i]);
    o[4 + i] = (bf16_t)(w1[i] * (v[4 + i] - mean) * rstd + b1[i]);
  }
  *(bf16x8*)(h + tok * CC + c0) = o;
}

// ---- kv partial: block = (b,head,chunk of 256 tokens) ----
__global__ __launch_bounds__(256) void kv_partial_kernel(const bf16_t* __restrict__ h,
                                                         const float* __restrict__ klw,
                                                         const float* __restrict__ klb,
                                                         const float* __restrict__ vlw,
                                                         const float* __restrict__ vlb,
                                                         float* __restrict__ kvp) {
  __shared__ bf16_t kb[256 * 32];
  __shared__ bf16_t vb[256 * 32];
  __shared__ float scratch[192 * 16];   // 12KB
  const int tid = threadIdx.x;
  const int bh = blockIdx.x >> 6, chunk = blockIdx.x & 63;
  const int head = bh & 15;
  const int b = bh >> 4;
  const long tok0 = ((long)b << 14) + chunk * 256;
  const bf16_t* src = h + (tok0 + tid) * (long)CC + head * DD;
  float hv[32];
  {
    float s = 0.f, s2 = 0.f;
#pragma unroll
    for (int c = 0; c < 4; ++c) {
      const bf16x8 r = *(const bf16x8*)(src + c * 8);
#pragma unroll
      for (int j = 0; j < 8; ++j) {
        hv[c * 8 + j] = (float)r[j]; s += hv[c * 8 + j]; s2 += hv[c * 8 + j] * hv[c * 8 + j];
      }
    }
    const float mean = s * (1.f / 32.f);
    const float varu = fmaxf((s2 - 32.f * mean * mean) * (1.f / 31.f), 0.f);
    const float inv = 1.f / (sqrtf(varu) + 1e-5f);   // torch.std semantics
    const int sx = (tid >> 1) & 3;
#pragma unroll
    for (int c = 0; c < 4; ++c) {
      bf16x8 kc, vc;
#pragma unroll
      for (int j = 0; j < 8; ++j) {
        const int d = c * 8 + j;
        const float t = (hv[d] - mean) * inv;
        kc[j] = (bf16_t)(klw[head * DD + d] * t + klb[head * DD + d]);
        vc[j] = (bf16_t)(vlw[head * DD + d] * t + vlb[head * DD + d]);
      }
      *(bf16x8*)((char*)kb + tid * 64 + ((c ^ sx) * 16)) = kc;
      *(bf16x8*)((char*)vb + tid * 64 + ((c ^ sx) * 16)) = vc;
    }
  }
  __syncthreads();
  const int g = tid >> 6, l = tid & 63;
  const int d0 = (l >> 3) * 4, e0 = (l & 7) * 4;
  const int ck = (l >> 3) >> 1, hk = (l >> 3) & 1;
  const int ce = (l & 7) >> 1, he = l & 1;
  float a[4][4] = {};
  for (int t = g; t < 256; t += 4) {
    const int tx = (t >> 1) & 3;
    const bf16x4 kq = *(const bf16x4*)((const char*)kb + t * 64 + ((ck ^ tx) * 16) + hk * 8);
    const bf16x4 vq = *(const bf16x4*)((const char*)vb + t * 64 + ((ce ^ tx) * 16) + he * 8);
    float kf[4], vf[4];
#pragma unroll
    for (int i2 = 0; i2 < 4; ++i2) { kf[i2] = (float)kq[i2]; vf[i2] = (float)vq[i2]; }
#pragma unroll
    for (int i2 = 0; i2 < 4; ++i2)
#pragma unroll
      for (int j2 = 0; j2 < 4; ++j2) a[i2][j2] += kf[i2] * vf[j2];
  }
  __syncthreads();
  if (g) {
#pragma unroll
    for (int i2 = 0; i2 < 4; ++i2)
#pragma unroll
      for (int j2 = 0; j2 < 4; ++j2)
        scratch[((g - 1) * 64 + l) * 16 + i2 * 4 + j2] = a[i2][j2];
  }
  __syncthreads();
  if (!g) {
#pragma unroll
    for (int gg = 0; gg < 3; ++gg)
#pragma unroll
      for (int i2 = 0; i2 < 4; ++i2)
#pragma unroll
        for (int j2 = 0; j2 < 4; ++j2)
          a[i2][j2] += scratch[(gg * 64 + l) * 16 + i2 * 4 + j2];
    float* dst = kvp + ((long)(bh * 64 + chunk) << 10);
#pragma unroll
    for (int i2 = 0; i2 < 4; ++i2) {
      f32x4 st;
      st[0] = a[i2][0]; st[1] = a[i2][1]; st[2] = a[i2][2]; st[3] = a[i2][3];
      *(f32x4*)&dst[(d0 + i2) * 32 + e0] = st;
    }
  }
}

// ---- kv reduce over 64 chunks, /N, store TRANSPOSED bf16: kvT[bh][e][d] ----
__global__ __launch_bounds__(256) void kv_reduce_kernel(const float* __restrict__ kvp,
                                                        bf16_t* __restrict__ kvT) {
  const int bh = blockIdx.x;
  const int i4 = threadIdx.x * 4;
  const int d = i4 >> 5, e0 = i4 & 31;
  float s[4] = {};
  const float* p = kvp + ((long)bh << 16) + i4;
  for (int ch = 0; ch < 64; ++ch) {
    const f32x4 t = *(const f32x4*)(p + (ch << 10));
    s[0] += t[0]; s[1] += t[1]; s[2] += t[2]; s[3] += t[3];
  }
  const float sc = 1.f / (float)NN;
  bf16_t* q = kvT + ((long)bh << 10);
#pragma unroll
  for (int j = 0; j < 4; ++j) q[(e0 + j) * 32 + d] = (bf16_t)(s[j] * sc);
}

// ---- fused: MFMA attn + residuals -> x2 (d_out fp32), LN2 -> m (bf16) ----
#define ASTRIDE 520
__global__ __launch_bounds__(256) void attn_fused_kernel(const float* __restrict__ x,
                                                         const bf16_t* __restrict__ h,
                                                         const bf16_t* __restrict__ kvTg,
                                                         const float* __restrict__ n2w,
                                                         const float* __restrict__ n2b,
                                                         float* __restrict__ xout,
                                                         bf16_t* __restrict__ mout) {
  __shared__ bf16_t attn_s[32 * ASTRIDE];
  const int tid = threadIdx.x;
  const int wv = tid >> 6, lane = tid & 63;
  const int lr = lane & 15, kg = lane >> 4;
  const long tok0 = (long)blockIdx.x * 32;
  const int b = (int)(tok0 >> 14);
  const bf16_t* kvsrc = kvTg + ((long)b << 14);

  {
    const int tt = wv & 1, hh = wv >> 1;
    const bf16_t* arow = h + (tok0 + tt * 16 + lr) * (long)CC + kg * 8;
    const f32x4 zero = {};
#pragma unroll
    for (int hi = 0; hi < 8; ++hi) {
      const int hd = hh * 8 + hi;
      const bf16_t* kvh = kvsrc + (hd << 10) + kg * 8;
      const bf16x8 af = *(const bf16x8*)(arow + hd * DD);
      const bf16x8 b0 = *(const bf16x8*)(kvh + lr * 32);
      const bf16x8 b1 = *(const bf16x8*)(kvh + (16 + lr) * 32);
      const f32x4 a0 = __builtin_amdgcn_mfma_f32_16x16x32_bf16(af, b0, zero, 0, 0, 0);
      const f32x4 a1 = __builtin_amdgcn_mfma_f32_16x16x32_bf16(af, b1, zero, 0, 0, 0);
      const int rbase = tt * 16 + kg * 4;
#pragma unroll
      for (int rg = 0; rg < 4; ++rg) {
        attn_s[(rbase + rg) * ASTRIDE + hd * 32 + lr]      = (bf16_t)a0[rg];
        attn_s[(rbase + rg) * ASTRIDE + hd * 32 + 16 + lr] = (bf16_t)a1[rg];
      }
    }
  }
  __syncthreads();

  const int c0 = lane * 8;
  const f32x4 w0 = *(const f32x4*)(n2w + c0), w1 = *(const f32x4*)(n2w + c0 + 4);
  const f32x4 bb0 = *(const f32x4*)(n2b + c0), bb1 = *(const f32x4*)(n2b + c0 + 4);
  for (int it = 0; it < 8; ++it) {
    const int tl = wv * 8 + it;
    const long tok = tok0 + tl;
    const f32x4 xa = *(const f32x4*)(x + tok * CC + c0);
    const f32x4 xb = *(const f32x4*)(x + tok * CC + c0 + 4);
    const bf16x8 hv = *(const bf16x8*)(h + tok * CC + c0);
    const bf16x8 av = *(const bf16x8*)&attn_s[tl * ASTRIDE + c0];
    float x2[8];
#pragma unroll
    for (int i = 0; i < 4; ++i) {
      x2[i]     = xa[i] + (float)hv[i]     + (float)av[i];
      x2[4 + i] = xb[i] + (float)hv[4 + i] + (float)av[4 + i];
    }
    float s = 0.f, s2 = 0.f;
#pragma unroll
    for (int i = 0; i < 8; ++i) { s += x2[i]; s2 += x2[i] * x2[i]; }
    for (int off = 32; off; off >>= 1) { s += __shfl_xor(s, off); s2 += __shfl_xor(s2, off); }
    const float mean = s * (1.f / CC);
    const float var  = fmaxf(s2 * (1.f / CC) - mean * mean, 0.f);
    const float rstd = rsqrtf(var + 1e-5f);
    f32x4 oa, ob;
    bf16x8 om;
#pragma unroll
    for (int i = 0; i < 4; ++i) {
      oa[i] = x2[i]; ob[i] = x2[4 + i];
      om[i]     = (bf16_t)(w0[i] * (x2[i] - mean) * rstd + bb0[i]);
      om[4 + i] = (bf16_t)(w1[i] * (x2[4 + i] - mean) * rstd + bb1[i]);
    }
    *(f32x4*)(xout + tok * CC + c0) = oa;
    *(f32x4*)(xout + tok * CC + c0 + 4) = ob;
    *(bf16x8*)(mout + tok * CC + c0) = om;
  }
}

// ---- m97-style GEMM, BK=64, LDS exactly 32KB -> 5 blocks/CU (20 waves/CU) ----
// out[i][j] = sum_k A[i][k] * Bw[j][k]; XOR-swizzled both sides.
template <int K, int NOUT, bool GELU>
__global__ __launch_bounds__(256, 5) void gemm97_kernel(const bf16_t* __restrict__ A,
                                                        const bf16_t* __restrict__ Bw,
                                                        const float* __restrict__ bias,
                                                        bf16_t* __restrict__ outb,
                                                        float* __restrict__ outf) {
  constexpr int NTILE = NOUT / 128;
  constexpr int NT = K / 64;
  __shared__ char lds[32768];   // A[2ks][128][32e] 16KB + B same 16KB; epilogue reuses
  char* As = lds;
  char* Bs = lds + 16384;

  const int tid = threadIdx.x;
  const int wid = tid >> 6, lane = tid & 63;
  const int wr = wid >> 1, wc = wid & 1;       // wave grid 2x2, wave out 64x64
  const int lr = lane & 15, kg = lane >> 4;

  int bid = blockIdx.x;
  const int qq = gridDim.x >> 3;
  bid = (bid & 7) * qq + (bid >> 3);           // XCD swizzle (grid % 8 == 0)
  const long row0 = (long)(bid / NTILE) * 128;
  const long col0 = (long)(bid % NTILE) * 128;

  // staging: srow = tid>>2 covers rows srow, srow+64 of each kslice;
  // source col pre-swizzled: LDS[row][chunk c] holds logical c ^ ((row>>1)&3)
  const int srow = tid >> 2;
  const int sce = (((tid & 3) ^ ((srow >> 1) & 3)) << 3);
  const bf16_t* gA = A + (row0 + srow) * (long)K + sce;
  const bf16_t* gB = Bw + (col0 + srow) * (long)K + sce;

  f32x4 acc[4][4] = {};

  // fragment-read bases: swizzled chunk is lane-only -> base + compile-time imm
  const int cx = ((kg ^ ((lr >> 1) & 3)) << 4);
  const char* aB = As + (wr * 64 + lr) * 64 + cx;
  const char* bB = Bs + (wc * 64 + lr) * 64 + cx;

  for (int kt = 0; kt < NT; ++kt) {
    // stage both kslices of A and B (8 instrs/thread, 32KB total)
    gload_lds16(gA + kt * 64,            As + tid * 16);
    gload_lds16(gA + 64L * K + kt * 64,  As + 4096 + tid * 16);
    gload_lds16(gA + kt * 64 + 32,           As + 8192 + tid * 16);
    gload_lds16(gA + 64L * K + kt * 64 + 32, As + 12288 + tid * 16);
    gload_lds16(gB + kt * 64,            Bs + tid * 16);
    gload_lds16(gB + 64L * K + kt * 64,  Bs + 4096 + tid * 16);
    gload_lds16(gB + kt * 64 + 32,           Bs + 8192 + tid * 16);
    gload_lds16(gB + 64L * K + kt * 64 + 32, Bs + 12288 + tid * 16);
    __syncthreads();
#pragma unroll
    for (int ks = 0; ks < 2; ++ks) {
      bf16x8 af[4], bf[4];
#pragma unroll
      for (int m = 0; m < 4; ++m) af[m] = *(const bf16x8*)(aB + ks * 8192 + m * 1024);
#pragma unroll
      for (int n = 0; n < 4; ++n) bf[n] = *(const bf16x8*)(bB + ks * 8192 + n * 1024);
#pragma unroll
      for (int m = 0; m < 4; ++m)
#pragma unroll
        for (int n = 0; n < 4; ++n)
          acc[m][n] = __builtin_amdgcn_mfma_f32_16x16x32_bf16(af[m], bf[n], acc[m][n], 0, 0, 0);
    }
    __syncthreads();
  }

  if constexpr (GELU) {
    // LDS-staged epilogue (reuses the 32KB): 256B-contiguous row writes
    bf16_t* ot = (bf16_t*)lds;                 // [128][128], chunk-XOR swizzled
#pragma unroll
    for (int n = 0; n < 4; ++n) {
      const int col = wc * 64 + n * 16 + lr;
      const float bs = bias[col0 + col];
#pragma unroll
      for (int m = 0; m < 4; ++m) {
#pragma unroll
        for (int rg = 0; rg < 4; ++rg) {
          const int row = wr * 64 + m * 16 + kg * 4 + rg;
          const float v = acc[m][n][rg] + bs;
          const float u = 0.7978845608028654f * (v + 0.044715f * v * v * v);
          const float gv = v / (1.f + __expf(-2.f * u));
          const int ch = (col >> 3) ^ ((row >> 2) & 3);
          ot[row * 128 + ch * 8 + (col & 7)] = (bf16_t)gv;
        }
      }
    }
    __syncthreads();
#pragma unroll
    for (int it2 = 0; it2 < 8; ++it2) {
      const int idx = it2 * 256 + tid;         // 128 rows x 16 chunks
      const int row = idx >> 4, ch = idx & 15;
      const int chs = ch ^ ((row >> 2) & 3);
      const bf16x8 vv = *(const bf16x8*)&ot[row * 128 + chs * 8];
      *(bf16x8*)(outb + (row0 + row) * NOUT + col0 + ch * 8) = vv;
    }
  } else {
    // fp32 residual RMW: 64B-per-row sectors, clean
#pragma unroll
    for (int n = 0; n < 4; ++n) {
      const long col = col0 + wc * 64 + n * 16 + lr;
      const float bs = bias[col];
#pragma unroll
      for (int m = 0; m < 4; ++m) {
#pragma unroll
        for (int rg = 0; rg < 4; ++rg) {
          const long row = row0 + wr * 64 + m * 16 + kg * 4 + rg;
          outf[row * NOUT + col] += acc[m][n][rg] + bs;
        }
      }
    }
  }
}

extern "C" void kernel_launch(void* const* d_in, const int* in_sizes, int n_in,
                              void* d_out, int out_size, void* d_ws, size_t ws_size,
                              hipStream_t stream) {
  const float* x   = (const float*)d_in[0];
  const float* n1w = (const float*)d_in[2];
  const float* n1b = (const float*)d_in[3];
  const float* klw = (const float*)d_in[4];
  const float* klb = (const float*)d_in[5];
  const float* vlw = (const float*)d_in[6];
  const float* vlb = (const float*)d_in[7];
  const float* n2w = (const float*)d_in[8];
  const float* n2b = (const float*)d_in[9];
  const float* w1f = (const float*)d_in[10];
  const float* b1  = (const float*)d_in[11];
  const float* w2f = (const float*)d_in[12];
  const float* b2  = (const float*)d_in[13];
  float* out = (float*)d_out;

  int nch;
  if (ws_size >= 289538048ULL) nch = 2;
  else                         nch = 4;
  const long mch = MTOT / nch;

  char* ws = (char*)d_ws;
  size_t off = 0;
  bf16_t* h   = (bf16_t*)(ws + off); off += (size_t)MTOT * CC * 2;      // 64 MiB
  bf16_t* mb  = (bf16_t*)(ws + off); off += (size_t)MTOT * CC * 2;      // 64 MiB
  bf16_t* act = (bf16_t*)(ws + off); off += (size_t)mch * HID * 2;      // 256/nch MiB
  bf16_t* w1  = (bf16_t*)(ws + off); off += (size_t)HID * CC * 2;       // 2 MiB
  bf16_t* w2  = (bf16_t*)(ws + off); off += (size_t)HID * CC * 2;       // 2 MiB
  float*  kvp = (float*)(ws + off);  off += (size_t)BB * HH * 64 * 1024 * 4; // 16 MiB
  bf16_t* kvT = (bf16_t*)(ws + off);                                    // 128 KiB

  cvt_bf16_kernel<<<1024, 256, 0, stream>>>(w1f, w1);
  cvt_bf16_kernel<<<1024, 256, 0, stream>>>(w2f, w2);
  norm1_kernel<<<MTOT / 4, 256, 0, stream>>>(x, n1w, n1b, h);
  kv_partial_kernel<<<BB * HH * 64, 256, 0, stream>>>(h, klw, klb, vlw, vlb, kvp);
  kv_reduce_kernel<<<BB * HH, 256, 0, stream>>>(kvp, kvT);
  attn_fused_kernel<<<MTOT / 32, 256, 0, stream>>>(x, h, kvT, n2w, n2b, out, mb);
  for (int ch = 0; ch < nch; ++ch) {
    gemm97_kernel<CC, HID, true>
        <<<(int)((mch / 128) * (HID / 128)), 256, 0, stream>>>(
        mb + (size_t)ch * mch * CC, w1, b1, act, nullptr);
    gemm97_kernel<HID, CC, false>
        <<<(int)((mch / 128) * (CC / 128)), 256, 0, stream>>>(
        act, w2, b2, nullptr, out + (size_t)ch * mch * CC);
  }
}

// Round 12
// 729.802 us; speedup vs baseline: 1.1218x; 1.1218x over previous
//
#include <hip/hip_runtime.h>
#include <cstdint>

// Problem constants
#define BB 4
#define NN 16384
#define CC 512
#define HH 16
#define DD 32
#define HID 2048
#define MTOT (BB * NN)        // 65536 tokens

typedef __bf16 bf16_t;
typedef __bf16 bf16x8 __attribute__((ext_vector_type(8)));
typedef __bf16 bf16x4 __attribute__((ext_vector_type(4)));
typedef float  f32x4  __attribute__((ext_vector_type(4)));

// ---- async global->LDS 16B ----
__device__ __forceinline__ void gload_lds16(const void* g, void* l) {
  auto gp = reinterpret_cast<const __attribute__((address_space(1))) char*>(
      reinterpret_cast<uintptr_t>(g));
  auto lp = reinterpret_cast<__attribute__((address_space(3))) char*>(
      reinterpret_cast<uintptr_t>(l));
  __builtin_amdgcn_global_load_lds(gp, lp, 16, 0, 0);
}

// ---- fp32 -> bf16 weight convert ----
__global__ __launch_bounds__(256) void cvt_bf16_kernel(const float* __restrict__ src,
                                                       bf16_t* __restrict__ dst) {
  const long i = ((long)blockIdx.x * 256 + threadIdx.x) * 4;
  const f32x4 v = *(const f32x4*)(src + i);
  bf16x4 o;
  o[0] = (bf16_t)v[0]; o[1] = (bf16_t)v[1]; o[2] = (bf16_t)v[2]; o[3] = (bf16_t)v[3];
  *(bf16x4*)(dst + i) = o;
}

// ---- LayerNorm1: one wave per token; lane owns 8 contiguous channels ----
__global__ __launch_bounds__(256) void norm1_kernel(const float* __restrict__ x,
                                                    const float* __restrict__ w,
                                                    const float* __restrict__ bvec,
                                                    bf16_t* __restrict__ h) {
  const int wv = threadIdx.x >> 6, l = threadIdx.x & 63;
  const long tok = (long)blockIdx.x * 4 + wv;
  const int c0 = l * 8;
  const f32x4 a = *(const f32x4*)(x + tok * CC + c0);
  const f32x4 b = *(const f32x4*)(x + tok * CC + c0 + 4);
  float v[8];
#pragma unroll
  for (int i = 0; i < 4; ++i) { v[i] = a[i]; v[4 + i] = b[i]; }
  float s = 0.f, s2 = 0.f;
#pragma unroll
  for (int i = 0; i < 8; ++i) { s += v[i]; s2 += v[i] * v[i]; }
  for (int off = 32; off; off >>= 1) { s += __shfl_xor(s, off); s2 += __shfl_xor(s2, off); }
  const float mean = s * (1.f / CC);
  const float var  = fmaxf(s2 * (1.f / CC) - mean * mean, 0.f);
  const float rstd = rsqrtf(var + 1e-5f);
  const f32x4 w0 = *(const f32x4*)(w + c0), w1 = *(const f32x4*)(w + c0 + 4);
  const f32x4 b0 = *(const f32x4*)(bvec + c0), b1 = *(const f32x4*)(bvec + c0 + 4);
  bf16x8 o;
#pragma unroll
  for (int i = 0; i < 4; ++i) {
    o[i]     = (bf16_t)(w0[i] * (v[i] - mean) * rstd + b0[i]);
    o[4 + i] = (bf16_t)(w1[i] * (v[4 + i] - mean) * rstd + b1[i]);
  }
  *(bf16x8*)(h + tok * CC + c0) = o;
}

// ---- kv partial: block = (b,head,chunk of 256 tokens) ----
__global__ __launch_bounds__(256) void kv_partial_kernel(const bf16_t* __restrict__ h,
                                                         const float* __restrict__ klw,
                                                         const float* __restrict__ klb,
                                                         const float* __restrict__ vlw,
                                                         const float* __restrict__ vlb,
                                                         float* __restrict__ kvp) {
  __shared__ bf16_t kb[256 * 32];
  __shared__ bf16_t vb[256 * 32];
  __shared__ float scratch[192 * 16];   // 12KB
  const int tid = threadIdx.x;
  const int bh = blockIdx.x >> 6, chunk = blockIdx.x & 63;
  const int head = bh & 15;
  const int b = bh >> 4;
  const long tok0 = ((long)b << 14) + chunk * 256;
  const bf16_t* src = h + (tok0 + tid) * (long)CC + head * DD;
  float hv[32];
  {
    float s = 0.f, s2 = 0.f;
#pragma unroll
    for (int c = 0; c < 4; ++c) {
      const bf16x8 r = *(const bf16x8*)(src + c * 8);
#pragma unroll
      for (int j = 0; j < 8; ++j) {
        hv[c * 8 + j] = (float)r[j]; s += hv[c * 8 + j]; s2 += hv[c * 8 + j] * hv[c * 8 + j];
      }
    }
    const float mean = s * (1.f / 32.f);
    const float varu = fmaxf((s2 - 32.f * mean * mean) * (1.f / 31.f), 0.f);
    const float inv = 1.f / (sqrtf(varu) + 1e-5f);   // torch.std semantics
    const int sx = (tid >> 1) & 3;
#pragma unroll
    for (int c = 0; c < 4; ++c) {
      bf16x8 kc, vc;
#pragma unroll
      for (int j = 0; j < 8; ++j) {
        const int d = c * 8 + j;
        const float t = (hv[d] - mean) * inv;
        kc[j] = (bf16_t)(klw[head * DD + d] * t + klb[head * DD + d]);
        vc[j] = (bf16_t)(vlw[head * DD + d] * t + vlb[head * DD + d]);
      }
      *(bf16x8*)((char*)kb + tid * 64 + ((c ^ sx) * 16)) = kc;
      *(bf16x8*)((char*)vb + tid * 64 + ((c ^ sx) * 16)) = vc;
    }
  }
  __syncthreads();
  const int g = tid >> 6, l = tid & 63;
  const int d0 = (l >> 3) * 4, e0 = (l & 7) * 4;
  const int ck = (l >> 3) >> 1, hk = (l >> 3) & 1;
  const int ce = (l & 7) >> 1, he = l & 1;
  float a[4][4] = {};
  for (int t = g; t < 256; t += 4) {
    const int tx = (t >> 1) & 3;
    const bf16x4 kq = *(const bf16x4*)((const char*)kb + t * 64 + ((ck ^ tx) * 16) + hk * 8);
    const bf16x4 vq = *(const bf16x4*)((const char*)vb + t * 64 + ((ce ^ tx) * 16) + he * 8);
    float kf[4], vf[4];
#pragma unroll
    for (int i2 = 0; i2 < 4; ++i2) { kf[i2] = (float)kq[i2]; vf[i2] = (float)vq[i2]; }
#pragma unroll
    for (int i2 = 0; i2 < 4; ++i2)
#pragma unroll
      for (int j2 = 0; j2 < 4; ++j2) a[i2][j2] += kf[i2] * vf[j2];
  }
  __syncthreads();
  if (g) {
#pragma unroll
    for (int i2 = 0; i2 < 4; ++i2)
#pragma unroll
      for (int j2 = 0; j2 < 4; ++j2)
        scratch[((g - 1) * 64 + l) * 16 + i2 * 4 + j2] = a[i2][j2];
  }
  __syncthreads();
  if (!g) {
#pragma unroll
    for (int gg = 0; gg < 3; ++gg)
#pragma unroll
      for (int i2 = 0; i2 < 4; ++i2)
#pragma unroll
        for (int j2 = 0; j2 < 4; ++j2)
          a[i2][j2] += scratch[(gg * 64 + l) * 16 + i2 * 4 + j2];
    float* dst = kvp + ((long)(bh * 64 + chunk) << 10);
#pragma unroll
    for (int i2 = 0; i2 < 4; ++i2) {
      f32x4 st;
      st[0] = a[i2][0]; st[1] = a[i2][1]; st[2] = a[i2][2]; st[3] = a[i2][3];
      *(f32x4*)&dst[(d0 + i2) * 32 + e0] = st;
    }
  }
}

// ---- kv reduce over 64 chunks, /N, store TRANSPOSED bf16: kvT[bh][e][d] ----
__global__ __launch_bounds__(256) void kv_reduce_kernel(const float* __restrict__ kvp,
                                                        bf16_t* __restrict__ kvT) {
  const int bh = blockIdx.x;
  const int i4 = threadIdx.x * 4;
  const int d = i4 >> 5, e0 = i4 & 31;
  float s[4] = {};
  const float* p = kvp + ((long)bh << 16) + i4;
  for (int ch = 0; ch < 64; ++ch) {
    const f32x4 t = *(const f32x4*)(p + (ch << 10));
    s[0] += t[0]; s[1] += t[1]; s[2] += t[2]; s[3] += t[3];
  }
  const float sc = 1.f / (float)NN;
  bf16_t* q = kvT + ((long)bh << 10);
#pragma unroll
  for (int j = 0; j < 4; ++j) q[(e0 + j) * 32 + d] = (bf16_t)(s[j] * sc);
}

// ---- fused: MFMA attn + residuals -> x2 (d_out fp32), LN2 -> m (bf16) ----
#define ASTRIDE 520
__global__ __launch_bounds__(256) void attn_fused_kernel(const float* __restrict__ x,
                                                         const bf16_t* __restrict__ h,
                                                         const bf16_t* __restrict__ kvTg,
                                                         const float* __restrict__ n2w,
                                                         const float* __restrict__ n2b,
                                                         float* __restrict__ xout,
                                                         bf16_t* __restrict__ mout) {
  __shared__ bf16_t attn_s[32 * ASTRIDE];
  const int tid = threadIdx.x;
  const int wv = tid >> 6, lane = tid & 63;
  const int lr = lane & 15, kg = lane >> 4;
  const long tok0 = (long)blockIdx.x * 32;
  const int b = (int)(tok0 >> 14);
  const bf16_t* kvsrc = kvTg + ((long)b << 14);

  {
    const int tt = wv & 1, hh = wv >> 1;
    const bf16_t* arow = h + (tok0 + tt * 16 + lr) * (long)CC + kg * 8;
    const f32x4 zero = {};
#pragma unroll
    for (int hi = 0; hi < 8; ++hi) {
      const int hd = hh * 8 + hi;
      const bf16_t* kvh = kvsrc + (hd << 10) + kg * 8;
      const bf16x8 af = *(const bf16x8*)(arow + hd * DD);
      const bf16x8 b0 = *(const bf16x8*)(kvh + lr * 32);
      const bf16x8 b1 = *(const bf16x8*)(kvh + (16 + lr) * 32);
      const f32x4 a0 = __builtin_amdgcn_mfma_f32_16x16x32_bf16(af, b0, zero, 0, 0, 0);
      const f32x4 a1 = __builtin_amdgcn_mfma_f32_16x16x32_bf16(af, b1, zero, 0, 0, 0);
      const int rbase = tt * 16 + kg * 4;
#pragma unroll
      for (int rg = 0; rg < 4; ++rg) {
        attn_s[(rbase + rg) * ASTRIDE + hd * 32 + lr]      = (bf16_t)a0[rg];
        attn_s[(rbase + rg) * ASTRIDE + hd * 32 + 16 + lr] = (bf16_t)a1[rg];
      }
    }
  }
  __syncthreads();

  const int c0 = lane * 8;
  const f32x4 w0 = *(const f32x4*)(n2w + c0), w1 = *(const f32x4*)(n2w + c0 + 4);
  const f32x4 bb0 = *(const f32x4*)(n2b + c0), bb1 = *(const f32x4*)(n2b + c0 + 4);
  for (int it = 0; it < 8; ++it) {
    const int tl = wv * 8 + it;
    const long tok = tok0 + tl;
    const f32x4 xa = *(const f32x4*)(x + tok * CC + c0);
    const f32x4 xb = *(const f32x4*)(x + tok * CC + c0 + 4);
    const bf16x8 hv = *(const bf16x8*)(h + tok * CC + c0);
    const bf16x8 av = *(const bf16x8*)&attn_s[tl * ASTRIDE + c0];
    float x2[8];
#pragma unroll
    for (int i = 0; i < 4; ++i) {
      x2[i]     = xa[i] + (float)hv[i]     + (float)av[i];
      x2[4 + i] = xb[i] + (float)hv[4 + i] + (float)av[4 + i];
    }
    float s = 0.f, s2 = 0.f;
#pragma unroll
    for (int i = 0; i < 8; ++i) { s += x2[i]; s2 += x2[i] * x2[i]; }
    for (int off = 32; off; off >>= 1) { s += __shfl_xor(s, off); s2 += __shfl_xor(s2, off); }
    const float mean = s * (1.f / CC);
    const float var  = fmaxf(s2 * (1.f / CC) - mean * mean, 0.f);
    const float rstd = rsqrtf(var + 1e-5f);
    f32x4 oa, ob;
    bf16x8 om;
#pragma unroll
    for (int i = 0; i < 4; ++i) {
      oa[i] = x2[i]; ob[i] = x2[4 + i];
      om[i]     = (bf16_t)(w0[i] * (x2[i] - mean) * rstd + bb0[i]);
      om[4 + i] = (bf16_t)(w1[i] * (x2[4 + i] - mean) * rstd + bb1[i]);
    }
    *(f32x4*)(xout + tok * CC + c0) = oa;
    *(f32x4*)(xout + tok * CC + c0 + 4) = ob;
    *(bf16x8*)(mout + tok * CC + c0) = om;
  }
}

// ---- multi-tile persistent pipelined GEMM: 128x128 tile, BK=32, 5-buffer ring,
//      distance-4 prefetch (vmcnt(16) steady), TPB tiles per block sharing one
//      A row-strip; pipeline filled ONCE per block (fill/drain amortized). ----
// out[i][j] = sum_k A[i][k] * Bw[j][k]
template <int K, int NOUT, int TPB, bool GELU>
__global__ __launch_bounds__(256, 2) void gemm_pipe_kernel(const bf16_t* __restrict__ A,
                                                           const bf16_t* __restrict__ Bw,
                                                           const float* __restrict__ bias,
                                                           bf16_t* __restrict__ outb,
                                                           float* __restrict__ outf) {
  constexpr int NTK = K / 32;               // K-steps per tile
  constexpr int STOT = TPB * NTK;           // stage units per block
  constexpr int NTILE = NOUT / 128;
  constexpr int BPS = NTILE / TPB;          // blocks per row-strip
  __shared__ char lds[5 * 16384];           // 80KB ring -> 2 blocks/CU

  const int tid = threadIdx.x;
  const int wid = tid >> 6, lane = tid & 63;
  const int wr = wid >> 1, wc = wid & 1;    // wave grid 2x2, wave out 64x64
  const int lr = lane & 15, kg = lane >> 4;

  int bid = blockIdx.x;
  const int qq = gridDim.x >> 3;
  bid = (bid & 7) * qq + (bid >> 3);        // XCD swizzle (grid % 8 == 0)
  const int strip = bid / BPS;
  const int ct0 = (bid % BPS) * TPB;        // first col-tile of this block
  const long row0 = (long)strip * 128;

  const int srow = tid >> 2;                                   // 0..63
  const int sce = (((tid & 3) ^ ((srow >> 1) & 3)) << 3);      // pre-swizzled col
  const bf16_t* gA = A + (row0 + srow) * (long)K + sce;

  // fragment-read bases: swizzled chunk is lane-only -> base + ring offset
  const int cx = ((kg ^ ((lr >> 1) & 3)) << 4);
  const char* aBb = (const char*)lds + (wr * 64 + lr) * 64 + cx;
  const char* bBb = (const char*)lds + 8192 + (wc * 64 + lr) * 64 + cx;

  f32x4 acc[4][4] = {};

  auto STAGE = [&](int s) {
    const int tp = s / NTK, kt = s % NTK, buf = s % 5;
    char* d = (char*)lds + buf * 16384 + tid * 16;
    const bf16_t* ga = gA + kt * 32;
    gload_lds16(ga, d);
    gload_lds16(ga + 64L * K, d + 4096);
    const bf16_t* gb = Bw + ((long)(ct0 + tp) * 128 + srow) * K + sce + kt * 32;
    gload_lds16(gb, d + 8192);
    gload_lds16(gb + 64L * K, d + 12288);
  };

  // prologue: fill 4 units
  STAGE(0); STAGE(1); STAGE(2); STAGE(3);

#pragma unroll 5
  for (int s = 0; s < STOT; ++s) {
    if (s + 4 < STOT) STAGE(s + 4);
    const int rem = STOT - 1 - s;
    if (rem >= 4)      asm volatile("s_waitcnt vmcnt(16)" ::: "memory");
    else if (rem == 3) asm volatile("s_waitcnt vmcnt(12)" ::: "memory");
    else if (rem == 2) asm volatile("s_waitcnt vmcnt(8)" ::: "memory");
    else if (rem == 1) asm volatile("s_waitcnt vmcnt(4)" ::: "memory");
    else               asm volatile("s_waitcnt vmcnt(0)" ::: "memory");
    __builtin_amdgcn_s_barrier();
    const int buf = s % 5;
    const char* aB = aBb + buf * 16384;
    const char* bB = bBb + buf * 16384;
    bf16x8 af[4], bf[4];
#pragma unroll
    for (int m = 0; m < 4; ++m) af[m] = *(const bf16x8*)(aB + m * 1024);
#pragma unroll
    for (int n = 0; n < 4; ++n) bf[n] = *(const bf16x8*)(bB + n * 1024);
#pragma unroll
    for (int m = 0; m < 4; ++m)
#pragma unroll
      for (int n = 0; n < 4; ++n)
        acc[m][n] = __builtin_amdgcn_mfma_f32_16x16x32_bf16(af[m], bf[n], acc[m][n], 0, 0, 0);
    __builtin_amdgcn_s_barrier();
    if ((s % NTK) == NTK - 1) {
      // tile finished: epilogue (direct stores; no LDS - ring stays live)
      const long col0 = (long)(ct0 + s / NTK) * 128;
#pragma unroll
      for (int n = 0; n < 4; ++n) {
        const long col = col0 + wc * 64 + n * 16 + lr;
        const float bs = bias[col];
#pragma unroll
        for (int m = 0; m < 4; ++m) {
#pragma unroll
          for (int rg = 0; rg < 4; ++rg) {
            const long row = row0 + wr * 64 + m * 16 + kg * 4 + rg;
            const float v = acc[m][n][rg] + bs;
            if constexpr (GELU) {
              const float u = 0.7978845608028654f * (v + 0.044715f * v * v * v);
              const float gv = v / (1.f + __expf(-2.f * u));
              outb[row * NOUT + col] = (bf16_t)gv;
            } else {
              outf[row * NOUT + col] += v;   // residual RMW onto x2 in d_out
            }
          }
        }
      }
#pragma unroll
      for (int m = 0; m < 4; ++m)
#pragma unroll
        for (int n = 0; n < 4; ++n)
          acc[m][n] = f32x4{};
    }
  }
}

extern "C" void kernel_launch(void* const* d_in, const int* in_sizes, int n_in,
                              void* d_out, int out_size, void* d_ws, size_t ws_size,
                              hipStream_t stream) {
  const float* x   = (const float*)d_in[0];
  const float* n1w = (const float*)d_in[2];
  const float* n1b = (const float*)d_in[3];
  const float* klw = (const float*)d_in[4];
  const float* klb = (const float*)d_in[5];
  const float* vlw = (const float*)d_in[6];
  const float* vlb = (const float*)d_in[7];
  const float* n2w = (const float*)d_in[8];
  const float* n2b = (const float*)d_in[9];
  const float* w1f = (const float*)d_in[10];
  const float* b1  = (const float*)d_in[11];
  const float* w2f = (const float*)d_in[12];
  const float* b2  = (const float*)d_in[13];
  float* out = (float*)d_out;

  int nch;
  if (ws_size >= 289538048ULL) nch = 2;
  else                         nch = 4;
  const long mch = MTOT / nch;

  char* ws = (char*)d_ws;
  size_t off = 0;
  bf16_t* h   = (bf16_t*)(ws + off); off += (size_t)MTOT * CC * 2;      // 64 MiB
  bf16_t* mb  = (bf16_t*)(ws + off); off += (size_t)MTOT * CC * 2;      // 64 MiB
  bf16_t* act = (bf16_t*)(ws + off); off += (size_t)mch * HID * 2;      // 256/nch MiB
  bf16_t* w1  = (bf16_t*)(ws + off); off += (size_t)HID * CC * 2;       // 2 MiB
  bf16_t* w2  = (bf16_t*)(ws + off); off += (size_t)HID * CC * 2;       // 2 MiB
  float*  kvp = (float*)(ws + off);  off += (size_t)BB * HH * 64 * 1024 * 4; // 16 MiB
  bf16_t* kvT = (bf16_t*)(ws + off);                                    // 128 KiB

  cvt_bf16_kernel<<<1024, 256, 0, stream>>>(w1f, w1);
  cvt_bf16_kernel<<<1024, 256, 0, stream>>>(w2f, w2);
  norm1_kernel<<<MTOT / 4, 256, 0, stream>>>(x, n1w, n1b, h);
  kv_partial_kernel<<<BB * HH * 64, 256, 0, stream>>>(h, klw, klb, vlw, vlb, kvp);
  kv_reduce_kernel<<<BB * HH, 256, 0, stream>>>(kvp, kvT);
  attn_fused_kernel<<<MTOT / 32, 256, 0, stream>>>(x, h, kvT, n2w, n2b, out, mb);
  for (int ch = 0; ch < nch; ++ch) {
    // GEMM1: tiles = (mch/128) x 16; TPB=8 -> grid (mch/128)*2, 128 K-steps/block
    gemm_pipe_kernel<CC, HID, 8, true>
        <<<(int)((mch / 128) * 2), 256, 0, stream>>>(
        mb + (size_t)ch * mch * CC, w1, b1, act, nullptr);
    // GEMM2: tiles = (mch/128) x 4; TPB=4 -> grid (mch/128), 256 K-steps/block
    gemm_pipe_kernel<HID, CC, 4, false>
        <<<(int)(mch / 128), 256, 0, stream>>>(
        act, w2, b2, nullptr, out + (size_t)ch * mch * CC);
  }
}

// Round 13
// 601.683 us; speedup vs baseline: 1.3607x; 1.2129x over previous
//
#include <hip/hip_runtime.h>
#include <cstdint>

// Problem constants
#define BB 4
#define NN 16384
#define CC 512
#define HH 16
#define DD 32
#define HID 2048
#define MTOT (BB * NN)        // 65536 tokens

typedef __bf16 bf16_t;
typedef __bf16 bf16x8 __attribute__((ext_vector_type(8)));
typedef __bf16 bf16x4 __attribute__((ext_vector_type(4)));
typedef float  f32x4  __attribute__((ext_vector_type(4)));

// ---- async global->LDS 16B ----
__device__ __forceinline__ void gload_lds16(const void* g, void* l) {
  auto gp = reinterpret_cast<const __attribute__((address_space(1))) char*>(
      reinterpret_cast<uintptr_t>(g));
  auto lp = reinterpret_cast<__attribute__((address_space(3))) char*>(
      reinterpret_cast<uintptr_t>(l));
  __builtin_amdgcn_global_load_lds(gp, lp, 16, 0, 0);
}

// ---- fp32 -> bf16 weight convert ----
__global__ __launch_bounds__(256) void cvt_bf16_kernel(const float* __restrict__ src,
                                                       bf16_t* __restrict__ dst) {
  const long i = ((long)blockIdx.x * 256 + threadIdx.x) * 4;
  const f32x4 v = *(const f32x4*)(src + i);
  bf16x4 o;
  o[0] = (bf16_t)v[0]; o[1] = (bf16_t)v[1]; o[2] = (bf16_t)v[2]; o[3] = (bf16_t)v[3];
  *(bf16x4*)(dst + i) = o;
}

// ---- LayerNorm1: one wave per token; lane owns 8 contiguous channels ----
__global__ __launch_bounds__(256) void norm1_kernel(const float* __restrict__ x,
                                                    const float* __restrict__ w,
                                                    const float* __restrict__ bvec,
                                                    bf16_t* __restrict__ h) {
  const int wv = threadIdx.x >> 6, l = threadIdx.x & 63;
  const long tok = (long)blockIdx.x * 4 + wv;
  const int c0 = l * 8;
  const f32x4 a = *(const f32x4*)(x + tok * CC + c0);
  const f32x4 b = *(const f32x4*)(x + tok * CC + c0 + 4);
  float v[8];
#pragma unroll
  for (int i = 0; i < 4; ++i) { v[i] = a[i]; v[4 + i] = b[i]; }
  float s = 0.f, s2 = 0.f;
#pragma unroll
  for (int i = 0; i < 8; ++i) { s += v[i]; s2 += v[i] * v[i]; }
  for (int off = 32; off; off >>= 1) { s += __shfl_xor(s, off); s2 += __shfl_xor(s2, off); }
  const float mean = s * (1.f / CC);
  const float var  = fmaxf(s2 * (1.f / CC) - mean * mean, 0.f);
  const float rstd = rsqrtf(var + 1e-5f);
  const f32x4 w0 = *(const f32x4*)(w + c0), w1 = *(const f32x4*)(w + c0 + 4);
  const f32x4 b0 = *(const f32x4*)(bvec + c0), b1 = *(const f32x4*)(bvec + c0 + 4);
  bf16x8 o;
#pragma unroll
  for (int i = 0; i < 4; ++i) {
    o[i]     = (bf16_t)(w0[i] * (v[i] - mean) * rstd + b0[i]);
    o[4 + i] = (bf16_t)(w1[i] * (v[4 + i] - mean) * rstd + b1[i]);
  }
  *(bf16x8*)(h + tok * CC + c0) = o;
}

// ---- kv partial: block = (b,head,chunk of 256 tokens) ----
__global__ __launch_bounds__(256) void kv_partial_kernel(const bf16_t* __restrict__ h,
                                                         const float* __restrict__ klw,
                                                         const float* __restrict__ klb,
                                                         const float* __restrict__ vlw,
                                                         const float* __restrict__ vlb,
                                                         float* __restrict__ kvp) {
  __shared__ bf16_t kb[256 * 32];
  __shared__ bf16_t vb[256 * 32];
  __shared__ float scratch[192 * 16];   // 12KB
  const int tid = threadIdx.x;
  const int bh = blockIdx.x >> 6, chunk = blockIdx.x & 63;
  const int head = bh & 15;
  const int b = bh >> 4;
  const long tok0 = ((long)b << 14) + chunk * 256;
  const bf16_t* src = h + (tok0 + tid) * (long)CC + head * DD;
  float hv[32];
  {
    float s = 0.f, s2 = 0.f;
#pragma unroll
    for (int c = 0; c < 4; ++c) {
      const bf16x8 r = *(const bf16x8*)(src + c * 8);
#pragma unroll
      for (int j = 0; j < 8; ++j) {
        hv[c * 8 + j] = (float)r[j]; s += hv[c * 8 + j]; s2 += hv[c * 8 + j] * hv[c * 8 + j];
      }
    }
    const float mean = s * (1.f / 32.f);
    const float varu = fmaxf((s2 - 32.f * mean * mean) * (1.f / 31.f), 0.f);
    const float inv = 1.f / (sqrtf(varu) + 1e-5f);   // torch.std semantics
    const int sx = (tid >> 1) & 3;
#pragma unroll
    for (int c = 0; c < 4; ++c) {
      bf16x8 kc, vc;
#pragma unroll
      for (int j = 0; j < 8; ++j) {
        const int d = c * 8 + j;
        const float t = (hv[d] - mean) * inv;
        kc[j] = (bf16_t)(klw[head * DD + d] * t + klb[head * DD + d]);
        vc[j] = (bf16_t)(vlw[head * DD + d] * t + vlb[head * DD + d]);
      }
      *(bf16x8*)((char*)kb + tid * 64 + ((c ^ sx) * 16)) = kc;
      *(bf16x8*)((char*)vb + tid * 64 + ((c ^ sx) * 16)) = vc;
    }
  }
  __syncthreads();
  const int g = tid >> 6, l = tid & 63;
  const int d0 = (l >> 3) * 4, e0 = (l & 7) * 4;
  const int ck = (l >> 3) >> 1, hk = (l >> 3) & 1;
  const int ce = (l & 7) >> 1, he = l & 1;
  float a[4][4] = {};
  for (int t = g; t < 256; t += 4) {
    const int tx = (t >> 1) & 3;
    const bf16x4 kq = *(const bf16x4*)((const char*)kb + t * 64 + ((ck ^ tx) * 16) + hk * 8);
    const bf16x4 vq = *(const bf16x4*)((const char*)vb + t * 64 + ((ce ^ tx) * 16) + he * 8);
    float kf[4], vf[4];
#pragma unroll
    for (int i2 = 0; i2 < 4; ++i2) { kf[i2] = (float)kq[i2]; vf[i2] = (float)vq[i2]; }
#pragma unroll
    for (int i2 = 0; i2 < 4; ++i2)
#pragma unroll
      for (int j2 = 0; j2 < 4; ++j2) a[i2][j2] += kf[i2] * vf[j2];
  }
  __syncthreads();
  if (g) {
#pragma unroll
    for (int i2 = 0; i2 < 4; ++i2)
#pragma unroll
      for (int j2 = 0; j2 < 4; ++j2)
        scratch[((g - 1) * 64 + l) * 16 + i2 * 4 + j2] = a[i2][j2];
  }
  __syncthreads();
  if (!g) {
#pragma unroll
    for (int gg = 0; gg < 3; ++gg)
#pragma unroll
      for (int i2 = 0; i2 < 4; ++i2)
#pragma unroll
        for (int j2 = 0; j2 < 4; ++j2)
          a[i2][j2] += scratch[(gg * 64 + l) * 16 + i2 * 4 + j2];
    float* dst = kvp + ((long)(bh * 64 + chunk) << 10);
#pragma unroll
    for (int i2 = 0; i2 < 4; ++i2) {
      f32x4 st;
      st[0] = a[i2][0]; st[1] = a[i2][1]; st[2] = a[i2][2]; st[3] = a[i2][3];
      *(f32x4*)&dst[(d0 + i2) * 32 + e0] = st;
    }
  }
}

// ---- kv reduce over 64 chunks, /N, store TRANSPOSED bf16: kvT[bh][e][d] ----
__global__ __launch_bounds__(256) void kv_reduce_kernel(const float* __restrict__ kvp,
                                                        bf16_t* __restrict__ kvT) {
  const int bh = blockIdx.x;
  const int i4 = threadIdx.x * 4;
  const int d = i4 >> 5, e0 = i4 & 31;
  float s[4] = {};
  const float* p = kvp + ((long)bh << 16) + i4;
  for (int ch = 0; ch < 64; ++ch) {
    const f32x4 t = *(const f32x4*)(p + (ch << 10));
    s[0] += t[0]; s[1] += t[1]; s[2] += t[2]; s[3] += t[3];
  }
  const float sc = 1.f / (float)NN;
  bf16_t* q = kvT + ((long)bh << 10);
#pragma unroll
  for (int j = 0; j < 4; ++j) q[(e0 + j) * 32 + d] = (bf16_t)(s[j] * sc);
}

// ---- fused: MFMA attn + residuals -> x2 (d_out fp32), LN2 -> m (bf16) ----
// Phase 2 now software-pipelined depth-1: x/h loads for it+1 issue during it.
#define ASTRIDE 520
__global__ __launch_bounds__(256) void attn_fused_kernel(const float* __restrict__ x,
                                                         const bf16_t* __restrict__ h,
                                                         const bf16_t* __restrict__ kvTg,
                                                         const float* __restrict__ n2w,
                                                         const float* __restrict__ n2b,
                                                         float* __restrict__ xout,
                                                         bf16_t* __restrict__ mout) {
  __shared__ bf16_t attn_s[32 * ASTRIDE];
  const int tid = threadIdx.x;
  const int wv = tid >> 6, lane = tid & 63;
  const int lr = lane & 15, kg = lane >> 4;
  const long tok0 = (long)blockIdx.x * 32;
  const int b = (int)(tok0 >> 14);
  const bf16_t* kvsrc = kvTg + ((long)b << 14);

  {
    const int tt = wv & 1, hh = wv >> 1;
    const bf16_t* arow = h + (tok0 + tt * 16 + lr) * (long)CC + kg * 8;
    const f32x4 zero = {};
#pragma unroll
    for (int hi = 0; hi < 8; ++hi) {
      const int hd = hh * 8 + hi;
      const bf16_t* kvh = kvsrc + (hd << 10) + kg * 8;
      const bf16x8 af = *(const bf16x8*)(arow + hd * DD);
      const bf16x8 b0 = *(const bf16x8*)(kvh + lr * 32);
      const bf16x8 b1 = *(const bf16x8*)(kvh + (16 + lr) * 32);
      const f32x4 a0 = __builtin_amdgcn_mfma_f32_16x16x32_bf16(af, b0, zero, 0, 0, 0);
      const f32x4 a1 = __builtin_amdgcn_mfma_f32_16x16x32_bf16(af, b1, zero, 0, 0, 0);
      const int rbase = tt * 16 + kg * 4;
#pragma unroll
      for (int rg = 0; rg < 4; ++rg) {
        attn_s[(rbase + rg) * ASTRIDE + hd * 32 + lr]      = (bf16_t)a0[rg];
        attn_s[(rbase + rg) * ASTRIDE + hd * 32 + 16 + lr] = (bf16_t)a1[rg];
      }
    }
  }

  const int c0 = lane * 8;
  const f32x4 w0 = *(const f32x4*)(n2w + c0), w1 = *(const f32x4*)(n2w + c0 + 4);
  const f32x4 bb0 = *(const f32x4*)(n2b + c0), bb1 = *(const f32x4*)(n2b + c0 + 4);

  // preload it=0 BEFORE the barrier (independent of attn_s)
  const long tokp = tok0 + wv * 8;
  f32x4 xa = *(const f32x4*)(x + tokp * CC + c0);
  f32x4 xb = *(const f32x4*)(x + tokp * CC + c0 + 4);
  bf16x8 hv = *(const bf16x8*)(h + tokp * CC + c0);
  __syncthreads();

#pragma unroll
  for (int it = 0; it < 8; ++it) {
    const int tl = wv * 8 + it;
    const long tok = tok0 + tl;
    f32x4 xa1, xb1;
    bf16x8 hv1;
    if (it < 7) {   // issue next-iteration loads early; retire under compute+stores
      xa1 = *(const f32x4*)(x + (tok + 1) * CC + c0);
      xb1 = *(const f32x4*)(x + (tok + 1) * CC + c0 + 4);
      hv1 = *(const bf16x8*)(h + (tok + 1) * CC + c0);
    }
    const bf16x8 av = *(const bf16x8*)&attn_s[tl * ASTRIDE + c0];
    float x2[8];
#pragma unroll
    for (int i = 0; i < 4; ++i) {
      x2[i]     = xa[i] + (float)hv[i]     + (float)av[i];
      x2[4 + i] = xb[i] + (float)hv[4 + i] + (float)av[4 + i];
    }
    float s = 0.f, s2 = 0.f;
#pragma unroll
    for (int i = 0; i < 8; ++i) { s += x2[i]; s2 += x2[i] * x2[i]; }
    for (int off = 32; off; off >>= 1) { s += __shfl_xor(s, off); s2 += __shfl_xor(s2, off); }
    const float mean = s * (1.f / CC);
    const float var  = fmaxf(s2 * (1.f / CC) - mean * mean, 0.f);
    const float rstd = rsqrtf(var + 1e-5f);
    f32x4 oa, ob;
    bf16x8 om;
#pragma unroll
    for (int i = 0; i < 4; ++i) {
      oa[i] = x2[i]; ob[i] = x2[4 + i];
      om[i]     = (bf16_t)(w0[i] * (x2[i] - mean) * rstd + bb0[i]);
      om[4 + i] = (bf16_t)(w1[i] * (x2[4 + i] - mean) * rstd + bb1[i]);
    }
    *(f32x4*)(xout + tok * CC + c0) = oa;
    *(f32x4*)(xout + tok * CC + c0 + 4) = ob;
    *(bf16x8*)(mout + tok * CC + c0) = om;
    xa = xa1; xb = xb1; hv = hv1;
  }
}

// ---- 8-phase GEMM (round-6 config, best measured): BM=256, BK=64, 8 waves 2Mx4N,
//      deep-pipeline counted vmcnt (units waited 4 phases after issue). ----
template <int K, int NOUT, int BN, bool GELU>
__global__ __launch_bounds__(512, 2) void gemm8p_kernel(const bf16_t* __restrict__ A,
                                                        const bf16_t* __restrict__ Bw,
                                                        const float* __restrict__ bias,
                                                        bf16_t* __restrict__ outb,
                                                        float* __restrict__ outf) {
  constexpr int NTILE = NOUT / BN;
  constexpr int NT = K / 64;                 // K-tiles
  constexpr int NI = NT / 2;                 // iterations (2 K-tiles each)
  constexpr int WNSPAN = BN / 4;             // wave N span (64 or 32)
  constexpr int NH = WNSPAN / 32;            // frags per N-half (2 or 1)
  constexpr int NREP = 2 * NH;
  constexpr int BLOADS = BN / 128;           // B loads per ks-unit (2 or 1)
  constexpr int ABYT = 32768;                // A bytes per buffer
  constexpr int BBYT = BN * 128;             // B bytes per buffer
  constexpr int BUFB = ABYT + BBYT;

  __shared__ char lds[2 * BUFB];

  const int tid = threadIdx.x;
  const int wid = tid >> 6, lane = tid & 63;
  const int wm = wid >> 2, wn = wid & 3;
  const int lr = lane & 15, kg = lane >> 4;

  int bid = blockIdx.x;
  const int qq = gridDim.x >> 3;
  bid = (bid & 7) * qq + (bid >> 3);        // XCD swizzle (grid % 8 == 0)
  const long row0 = (long)(bid / NTILE) * 256;
  const long col0 = (long)(bid % NTILE) * BN;

  const int srow = tid >> 2;                                   // 0..127
  const int sce = (((tid & 3) ^ ((srow >> 1) & 3)) << 3);      // pre-swizzled col
  const bf16_t* pA = A + (row0 + srow) * (long)K + sce;
  const bf16_t* pB = Bw + (col0 + srow) * (long)K + sce;
  char* ldsp = (char*)lds;

  auto SA = [&](int buf, int ks, int kt) {
    char* d_ = ldsp + buf * BUFB + ks * 16384 + tid * 16;
    const bf16_t* g_ = pA + (long)kt * 64 + ks * 32;
    gload_lds16(g_, d_);
    gload_lds16(g_ + 128L * K, d_ + 8192);
  };
  auto SB = [&](int buf, int ks, int kt) {
    char* d_ = ldsp + buf * BUFB + ABYT + ks * (BN * 64) + tid * 16;
    const bf16_t* g_ = pB + (long)kt * 64 + ks * 32;
    gload_lds16(g_, d_);
    if constexpr (BLOADS == 2) gload_lds16(g_ + 128L * K, d_ + 8192);
  };

  f32x4 acc[8][NREP] = {};
  bf16x8 af[8], bf[NH];

  auto LDA8 = [&](int buf, int ks) {
    const char* b_ = ldsp + buf * BUFB + ks * 16384;
#pragma unroll
    for (int m = 0; m < 8; ++m) {
      const int row = wm * 128 + m * 16 + lr;
      af[m] = *(const bf16x8*)(b_ + row * 64 + ((kg ^ ((row >> 1) & 3)) << 4));
    }
  };
  auto LDBN = [&](int buf, int ks, int nh) {
    const char* b_ = ldsp + buf * BUFB + ABYT + ks * (BN * 64);
#pragma unroll
    for (int n = 0; n < NH; ++n) {
      const int row = wn * WNSPAN + nh * (WNSPAN / 2) + n * 16 + lr;
      bf[n] = *(const bf16x8*)(b_ + row * 64 + ((kg ^ ((row >> 1) & 3)) << 4));
    }
  };
  auto MM = [&](int nh) {
    __builtin_amdgcn_s_setprio(1);
#pragma unroll
    for (int m = 0; m < 8; ++m)
#pragma unroll
      for (int n = 0; n < NH; ++n)
        acc[m][nh * NH + n] =
            __builtin_amdgcn_mfma_f32_16x16x32_bf16(af[m], bf[n], acc[m][nh * NH + n], 0, 0, 0);
    __builtin_amdgcn_s_setprio(0);
  };
  // wait leaving 2 units in flight (steady) / 1 unit (tail) / 0 (drain)
  auto W2U = [&]() {
    if constexpr (BLOADS == 2) asm volatile("s_waitcnt vmcnt(8)" ::: "memory");
    else                       asm volatile("s_waitcnt vmcnt(6)" ::: "memory");
  };
  auto W1U = [&]() {
    if constexpr (BLOADS == 2) asm volatile("s_waitcnt vmcnt(4)" ::: "memory");
    else                       asm volatile("s_waitcnt vmcnt(3)" ::: "memory");
  };
#define BARX() __builtin_amdgcn_s_barrier()
#define LGKM0() asm volatile("s_waitcnt lgkmcnt(0)" ::: "memory")
#define W0U() asm volatile("s_waitcnt vmcnt(0)" ::: "memory")

  // prologue: stage 3 units in consumption order; land unit 1 only
  SA(0, 0, 0); SB(0, 0, 0);
  SA(0, 1, 0); SB(0, 1, 0);
  SA(1, 0, 1); SB(1, 0, 1);
  W2U();
  BARX();

  for (int i = 0; i < NI; ++i) {
    const int t1 = 2 * i + 1, tA = 2 * i + 2, tB = 2 * i + 3;
    // p1: read b0k0 | stage b1k1.A
    LDA8(0, 0); LDBN(0, 0, 0); SA(1, 1, t1);
    BARX(); LGKM0(); MM(0); BARX();
    // p2: read b0k0 | stage b1k1.B | wait lands b0k1 (for p3)
    LDBN(0, 0, 1); SB(1, 1, t1);
    BARX(); LGKM0(); MM(1); W2U(); BARX();
    // p3: read b0k1 | stage next b0k0
    LDA8(0, 1); LDBN(0, 1, 0); if (tA < NT) SA(0, 0, tA);
    BARX(); LGKM0(); MM(0); BARX();
    // p4: read b0k1 | stage next b0k0.B | wait lands b1k0 (for p5)
    LDBN(0, 1, 1); if (tA < NT) SB(0, 0, tA);
    BARX(); LGKM0(); MM(1);
    if (tA < NT) W2U(); else W1U();
    BARX();
    // p5: read b1k0 | stage next b0k1
    LDA8(1, 0); LDBN(1, 0, 0); if (tA < NT) SA(0, 1, tA);
    BARX(); LGKM0(); MM(0); BARX();
    // p6: read b1k0 | stage next b0k1.B | wait lands b1k1 (for p7)
    LDBN(1, 0, 1); if (tA < NT) SB(0, 1, tA);
    BARX(); LGKM0(); MM(1);
    if (tA < NT) W2U(); else W0U();
    BARX();
    // p7: read b1k1 | stage next b1k0
    LDA8(1, 1); LDBN(1, 1, 0); if (tB < NT) SA(1, 0, tB);
    BARX(); LGKM0(); MM(0); BARX();
    // p8: read b1k1 | stage next b1k0.B | wait lands next b0k0 (for next p1)
    LDBN(1, 1, 1); if (tB < NT) SB(1, 0, tB);
    BARX(); LGKM0(); MM(1);
    if (tB < NT) W2U();
    BARX();
  }
#undef BARX
#undef LGKM0
#undef W0U

  // epilogue: D row = kg*4 + rg, col = lr
#pragma unroll
  for (int j = 0; j < NREP; ++j) {
    const long col = col0 + wn * WNSPAN + j * 16 + lr;
    const float bs = bias[col];
#pragma unroll
    for (int m = 0; m < 8; ++m) {
#pragma unroll
      for (int rg = 0; rg < 4; ++rg) {
        const long row = row0 + wm * 128 + m * 16 + kg * 4 + rg;
        const float v = acc[m][j][rg] + bs;
        if constexpr (GELU) {
          const float u = 0.7978845608028654f * (v + 0.044715f * v * v * v);
          const float gv = v / (1.f + __expf(-2.f * u));
          outb[row * NOUT + col] = (bf16_t)gv;
        } else {
          outf[row * NOUT + col] += v;   // residual RMW onto x2 already in d_out
        }
      }
    }
  }
}

extern "C" void kernel_launch(void* const* d_in, const int* in_sizes, int n_in,
                              void* d_out, int out_size, void* d_ws, size_t ws_size,
                              hipStream_t stream) {
  const float* x   = (const float*)d_in[0];
  const float* n1w = (const float*)d_in[2];
  const float* n1b = (const float*)d_in[3];
  const float* klw = (const float*)d_in[4];
  const float* klb = (const float*)d_in[5];
  const float* vlw = (const float*)d_in[6];
  const float* vlb = (const float*)d_in[7];
  const float* n2w = (const float*)d_in[8];
  const float* n2b = (const float*)d_in[9];
  const float* w1f = (const float*)d_in[10];
  const float* b1  = (const float*)d_in[11];
  const float* w2f = (const float*)d_in[12];
  const float* b2  = (const float*)d_in[13];
  float* out = (float*)d_out;

  // chunk count by available workspace (act = 256MiB/nch)
  int nch;
  if (ws_size >= 423755776ULL)      nch = 1;
  else if (ws_size >= 289538048ULL) nch = 2;
  else                              nch = 4;
  const long mch = MTOT / nch;

  char* ws = (char*)d_ws;
  size_t off = 0;
  bf16_t* h   = (bf16_t*)(ws + off); off += (size_t)MTOT * CC * 2;      // 64 MiB
  bf16_t* mb  = (bf16_t*)(ws + off); off += (size_t)MTOT * CC * 2;      // 64 MiB
  bf16_t* act = (bf16_t*)(ws + off); off += (size_t)mch * HID * 2;      // 256/nch MiB
  bf16_t* w1  = (bf16_t*)(ws + off); off += (size_t)HID * CC * 2;       // 2 MiB
  bf16_t* w2  = (bf16_t*)(ws + off); off += (size_t)HID * CC * 2;       // 2 MiB
  float*  kvp = (float*)(ws + off);  off += (size_t)BB * HH * 64 * 1024 * 4; // 16 MiB
  bf16_t* kvT = (bf16_t*)(ws + off);                                    // 128 KiB

  cvt_bf16_kernel<<<1024, 256, 0, stream>>>(w1f, w1);
  cvt_bf16_kernel<<<1024, 256, 0, stream>>>(w2f, w2);
  norm1_kernel<<<MTOT / 4, 256, 0, stream>>>(x, n1w, n1b, h);
  kv_partial_kernel<<<BB * HH * 64, 256, 0, stream>>>(h, klw, klb, vlw, vlb, kvp);
  kv_reduce_kernel<<<BB * HH, 256, 0, stream>>>(kvp, kvT);
  attn_fused_kernel<<<MTOT / 32, 256, 0, stream>>>(x, h, kvT, n2w, n2b, out, mb);
  for (int ch = 0; ch < nch; ++ch) {
    gemm8p_kernel<CC, HID, 256, true>
        <<<(int)((mch / 256) * (HID / 256)), 512, 0, stream>>>(
        mb + (size_t)ch * mch * CC, w1, b1, act, nullptr);
    if (mch >= 32768) {
      gemm8p_kernel<HID, CC, 256, false>
          <<<(int)((mch / 256) * (CC / 256)), 512, 0, stream>>>(
          act, w2, b2, nullptr, out + (size_t)ch * mch * CC);
    } else {
      gemm8p_kernel<HID, CC, 128, false>
          <<<(int)((mch / 256) * (CC / 128)), 512, 0, stream>>>(
          act, w2, b2, nullptr, out + (size_t)ch * mch * CC);
    }
  }
}

// Round 14
// 589.026 us; speedup vs baseline: 1.3900x; 1.0215x over previous
//
#include <hip/hip_runtime.h>
#include <cstdint>

// Problem constants
#define BB 4
#define NN 16384
#define CC 512
#define HH 16
#define DD 32
#define HID 2048
#define MTOT (BB * NN)        // 65536 tokens

typedef __bf16 bf16_t;
typedef __bf16 bf16x8 __attribute__((ext_vector_type(8)));
typedef __bf16 bf16x4 __attribute__((ext_vector_type(4)));
typedef float  f32x4  __attribute__((ext_vector_type(4)));
typedef float  f32x16 __attribute__((ext_vector_type(16)));

// ---- async global->LDS 16B ----
__device__ __forceinline__ void gload_lds16(const void* g, void* l) {
  auto gp = reinterpret_cast<const __attribute__((address_space(1))) char*>(
      reinterpret_cast<uintptr_t>(g));
  auto lp = reinterpret_cast<__attribute__((address_space(3))) char*>(
      reinterpret_cast<uintptr_t>(l));
  __builtin_amdgcn_global_load_lds(gp, lp, 16, 0, 0);
}

// ---- fp32 -> bf16 weight convert ----
__global__ __launch_bounds__(256) void cvt_bf16_kernel(const float* __restrict__ src,
                                                       bf16_t* __restrict__ dst) {
  const long i = ((long)blockIdx.x * 256 + threadIdx.x) * 4;
  const f32x4 v = *(const f32x4*)(src + i);
  bf16x4 o;
  o[0] = (bf16_t)v[0]; o[1] = (bf16_t)v[1]; o[2] = (bf16_t)v[2]; o[3] = (bf16_t)v[3];
  *(bf16x4*)(dst + i) = o;
}

// ---- LayerNorm1: one wave per token; lane owns 8 contiguous channels ----
__global__ __launch_bounds__(256) void norm1_kernel(const float* __restrict__ x,
                                                    const float* __restrict__ w,
                                                    const float* __restrict__ bvec,
                                                    bf16_t* __restrict__ h) {
  const int wv = threadIdx.x >> 6, l = threadIdx.x & 63;
  const long tok = (long)blockIdx.x * 4 + wv;
  const int c0 = l * 8;
  const f32x4 a = *(const f32x4*)(x + tok * CC + c0);
  const f32x4 b = *(const f32x4*)(x + tok * CC + c0 + 4);
  float v[8];
#pragma unroll
  for (int i = 0; i < 4; ++i) { v[i] = a[i]; v[4 + i] = b[i]; }
  float s = 0.f, s2 = 0.f;
#pragma unroll
  for (int i = 0; i < 8; ++i) { s += v[i]; s2 += v[i] * v[i]; }
  for (int off = 32; off; off >>= 1) { s += __shfl_xor(s, off); s2 += __shfl_xor(s2, off); }
  const float mean = s * (1.f / CC);
  const float var  = fmaxf(s2 * (1.f / CC) - mean * mean, 0.f);
  const float rstd = rsqrtf(var + 1e-5f);
  const f32x4 w0 = *(const f32x4*)(w + c0), w1 = *(const f32x4*)(w + c0 + 4);
  const f32x4 b0 = *(const f32x4*)(bvec + c0), b1 = *(const f32x4*)(bvec + c0 + 4);
  bf16x8 o;
#pragma unroll
  for (int i = 0; i < 4; ++i) {
    o[i]     = (bf16_t)(w0[i] * (v[i] - mean) * rstd + b0[i]);
    o[4 + i] = (bf16_t)(w1[i] * (v[4 + i] - mean) * rstd + b1[i]);
  }
  *(bf16x8*)(h + tok * CC + c0) = o;
}

// ---- kv partial: block = (b,head,chunk of 256 tokens) ----
__global__ __launch_bounds__(256) void kv_partial_kernel(const bf16_t* __restrict__ h,
                                                         const float* __restrict__ klw,
                                                         const float* __restrict__ klb,
                                                         const float* __restrict__ vlw,
                                                         const float* __restrict__ vlb,
                                                         float* __restrict__ kvp) {
  __shared__ bf16_t kb[256 * 32];
  __shared__ bf16_t vb[256 * 32];
  __shared__ float scratch[192 * 16];   // 12KB
  const int tid = threadIdx.x;
  const int bh = blockIdx.x >> 6, chunk = blockIdx.x & 63;
  const int head = bh & 15;
  const int b = bh >> 4;
  const long tok0 = ((long)b << 14) + chunk * 256;
  const bf16_t* src = h + (tok0 + tid) * (long)CC + head * DD;
  float hv[32];
  {
    float s = 0.f, s2 = 0.f;
#pragma unroll
    for (int c = 0; c < 4; ++c) {
      const bf16x8 r = *(const bf16x8*)(src + c * 8);
#pragma unroll
      for (int j = 0; j < 8; ++j) {
        hv[c * 8 + j] = (float)r[j]; s += hv[c * 8 + j]; s2 += hv[c * 8 + j] * hv[c * 8 + j];
      }
    }
    const float mean = s * (1.f / 32.f);
    const float varu = fmaxf((s2 - 32.f * mean * mean) * (1.f / 31.f), 0.f);
    const float inv = 1.f / (sqrtf(varu) + 1e-5f);   // torch.std semantics
    const int sx = (tid >> 1) & 3;
#pragma unroll
    for (int c = 0; c < 4; ++c) {
      bf16x8 kc, vc;
#pragma unroll
      for (int j = 0; j < 8; ++j) {
        const int d = c * 8 + j;
        const float t = (hv[d] - mean) * inv;
        kc[j] = (bf16_t)(klw[head * DD + d] * t + klb[head * DD + d]);
        vc[j] = (bf16_t)(vlw[head * DD + d] * t + vlb[head * DD + d]);
      }
      *(bf16x8*)((char*)kb + tid * 64 + ((c ^ sx) * 16)) = kc;
      *(bf16x8*)((char*)vb + tid * 64 + ((c ^ sx) * 16)) = vc;
    }
  }
  __syncthreads();
  const int g = tid >> 6, l = tid & 63;
  const int d0 = (l >> 3) * 4, e0 = (l & 7) * 4;
  const int ck = (l >> 3) >> 1, hk = (l >> 3) & 1;
  const int ce = (l & 7) >> 1, he = l & 1;
  float a[4][4] = {};
  for (int t = g; t < 256; t += 4) {
    const int tx = (t >> 1) & 3;
    const bf16x4 kq = *(const bf16x4*)((const char*)kb + t * 64 + ((ck ^ tx) * 16) + hk * 8);
    const bf16x4 vq = *(const bf16x4*)((const char*)vb + t * 64 + ((ce ^ tx) * 16) + he * 8);
    float kf[4], vf[4];
#pragma unroll
    for (int i2 = 0; i2 < 4; ++i2) { kf[i2] = (float)kq[i2]; vf[i2] = (float)vq[i2]; }
#pragma unroll
    for (int i2 = 0; i2 < 4; ++i2)
#pragma unroll
      for (int j2 = 0; j2 < 4; ++j2) a[i2][j2] += kf[i2] * vf[j2];
  }
  __syncthreads();
  if (g) {
#pragma unroll
    for (int i2 = 0; i2 < 4; ++i2)
#pragma unroll
      for (int j2 = 0; j2 < 4; ++j2)
        scratch[((g - 1) * 64 + l) * 16 + i2 * 4 + j2] = a[i2][j2];
  }
  __syncthreads();
  if (!g) {
#pragma unroll
    for (int gg = 0; gg < 3; ++gg)
#pragma unroll
      for (int i2 = 0; i2 < 4; ++i2)
#pragma unroll
        for (int j2 = 0; j2 < 4; ++j2)
          a[i2][j2] += scratch[(gg * 64 + l) * 16 + i2 * 4 + j2];
    float* dst = kvp + ((long)(bh * 64 + chunk) << 10);
#pragma unroll
    for (int i2 = 0; i2 < 4; ++i2) {
      f32x4 st;
      st[0] = a[i2][0]; st[1] = a[i2][1]; st[2] = a[i2][2]; st[3] = a[i2][3];
      *(f32x4*)&dst[(d0 + i2) * 32 + e0] = st;
    }
  }
}

// ---- kv reduce over 64 chunks, /N, store TRANSPOSED bf16: kvT[bh][e][d] ----
__global__ __launch_bounds__(256) void kv_reduce_kernel(const float* __restrict__ kvp,
                                                        bf16_t* __restrict__ kvT) {
  const int bh = blockIdx.x;
  const int i4 = threadIdx.x * 4;
  const int d = i4 >> 5, e0 = i4 & 31;
  float s[4] = {};
  const float* p = kvp + ((long)bh << 16) + i4;
  for (int ch = 0; ch < 64; ++ch) {
    const f32x4 t = *(const f32x4*)(p + (ch << 10));
    s[0] += t[0]; s[1] += t[1]; s[2] += t[2]; s[3] += t[3];
  }
  const float sc = 1.f / (float)NN;
  bf16_t* q = kvT + ((long)bh << 10);
#pragma unroll
  for (int j = 0; j < 4; ++j) q[(e0 + j) * 32 + d] = (bf16_t)(s[j] * sc);
}

// ---- fused: MFMA attn + residuals -> x2 (d_out fp32), LN2 -> m (bf16) ----
#define ASTRIDE 520
__global__ __launch_bounds__(256) void attn_fused_kernel(const float* __restrict__ x,
                                                         const bf16_t* __restrict__ h,
                                                         const bf16_t* __restrict__ kvTg,
                                                         const float* __restrict__ n2w,
                                                         const float* __restrict__ n2b,
                                                         float* __restrict__ xout,
                                                         bf16_t* __restrict__ mout) {
  __shared__ bf16_t attn_s[32 * ASTRIDE];
  const int tid = threadIdx.x;
  const int wv = tid >> 6, lane = tid & 63;
  const int lr = lane & 15, kg = lane >> 4;
  const long tok0 = (long)blockIdx.x * 32;
  const int b = (int)(tok0 >> 14);
  const bf16_t* kvsrc = kvTg + ((long)b << 14);

  {
    const int tt = wv & 1, hh = wv >> 1;
    const bf16_t* arow = h + (tok0 + tt * 16 + lr) * (long)CC + kg * 8;
    const f32x4 zero = {};
#pragma unroll
    for (int hi = 0; hi < 8; ++hi) {
      const int hd = hh * 8 + hi;
      const bf16_t* kvh = kvsrc + (hd << 10) + kg * 8;
      const bf16x8 af = *(const bf16x8*)(arow + hd * DD);
      const bf16x8 b0 = *(const bf16x8*)(kvh + lr * 32);
      const bf16x8 b1 = *(const bf16x8*)(kvh + (16 + lr) * 32);
      const f32x4 a0 = __builtin_amdgcn_mfma_f32_16x16x32_bf16(af, b0, zero, 0, 0, 0);
      const f32x4 a1 = __builtin_amdgcn_mfma_f32_16x16x32_bf16(af, b1, zero, 0, 0, 0);
      const int rbase = tt * 16 + kg * 4;
#pragma unroll
      for (int rg = 0; rg < 4; ++rg) {
        attn_s[(rbase + rg) * ASTRIDE + hd * 32 + lr]      = (bf16_t)a0[rg];
        attn_s[(rbase + rg) * ASTRIDE + hd * 32 + 16 + lr] = (bf16_t)a1[rg];
      }
    }
  }

  const int c0 = lane * 8;
  const f32x4 w0 = *(const f32x4*)(n2w + c0), w1 = *(const f32x4*)(n2w + c0 + 4);
  const f32x4 bb0 = *(const f32x4*)(n2b + c0), bb1 = *(const f32x4*)(n2b + c0 + 4);

  // preload it=0 BEFORE the barrier (independent of attn_s)
  const long tokp = tok0 + wv * 8;
  f32x4 xa = *(const f32x4*)(x + tokp * CC + c0);
  f32x4 xb = *(const f32x4*)(x + tokp * CC + c0 + 4);
  bf16x8 hv = *(const bf16x8*)(h + tokp * CC + c0);
  __syncthreads();

#pragma unroll
  for (int it = 0; it < 8; ++it) {
    const int tl = wv * 8 + it;
    const long tok = tok0 + tl;
    f32x4 xa1, xb1;
    bf16x8 hv1;
    if (it < 7) {
      xa1 = *(const f32x4*)(x + (tok + 1) * CC + c0);
      xb1 = *(const f32x4*)(x + (tok + 1) * CC + c0 + 4);
      hv1 = *(const bf16x8*)(h + (tok + 1) * CC + c0);
    }
    const bf16x8 av = *(const bf16x8*)&attn_s[tl * ASTRIDE + c0];
    float x2[8];
#pragma unroll
    for (int i = 0; i < 4; ++i) {
      x2[i]     = xa[i] + (float)hv[i]     + (float)av[i];
      x2[4 + i] = xb[i] + (float)hv[4 + i] + (float)av[4 + i];
    }
    float s = 0.f, s2 = 0.f;
#pragma unroll
    for (int i = 0; i < 8; ++i) { s += x2[i]; s2 += x2[i] * x2[i]; }
    for (int off = 32; off; off >>= 1) { s += __shfl_xor(s, off); s2 += __shfl_xor(s2, off); }
    const float mean = s * (1.f / CC);
    const float var  = fmaxf(s2 * (1.f / CC) - mean * mean, 0.f);
    const float rstd = rsqrtf(var + 1e-5f);
    f32x4 oa, ob;
    bf16x8 om;
#pragma unroll
    for (int i = 0; i < 4; ++i) {
      oa[i] = x2[i]; ob[i] = x2[4 + i];
      om[i]     = (bf16_t)(w0[i] * (x2[i] - mean) * rstd + bb0[i]);
      om[4 + i] = (bf16_t)(w1[i] * (x2[4 + i] - mean) * rstd + bb1[i]);
    }
    *(f32x4*)(xout + tok * CC + c0) = oa;
    *(f32x4*)(xout + tok * CC + c0 + 4) = ob;
    *(bf16x8*)(mout + tok * CC + c0) = om;
    xa = xa1; xb = xb1; hv = hv1;
  }
}

// ---- 8-phase GEMM (r6 schedule) with 32x32x16 MFMA: BM=256, BK=64, 8 waves 2Mx4N.
//      Wave out 128x(BN/4) = 4 x NF2 frags of 32x32. Per phase: 4+NF2 ds_read_b128,
//      4*NF2 MFMA. Staging/vmcnt ledger identical to the proven r6 schedule.
template <int K, int NOUT, int BN, bool GELU>
__global__ __launch_bounds__(512, 2) void gemm8p_kernel(const bf16_t* __restrict__ A,
                                                        const bf16_t* __restrict__ Bw,
                                                        const float* __restrict__ bias,
                                                        bf16_t* __restrict__ outb,
                                                        float* __restrict__ outf) {
  constexpr int NTILE = NOUT / BN;
  constexpr int NT = K / 64;                 // K-tiles
  constexpr int NI = NT / 2;                 // iterations (2 K-tiles each)
  constexpr int WNSPAN = BN / 4;             // wave N span (64 or 32)
  constexpr int NF2 = WNSPAN / 32;           // 32-wide N frags per wave (2 or 1)
  constexpr int BLOADS = BN / 128;           // B loads per ks-unit (2 or 1)
  constexpr int ABYT = 32768;                // A bytes per buffer
  constexpr int BBYT = BN * 128;             // B bytes per buffer
  constexpr int BUFB = ABYT + BBYT;
  constexpr int KSB = BN * 64;               // B kslice stride (bytes)

  __shared__ char lds[2 * BUFB];

  const int tid = threadIdx.x;
  const int wid = tid >> 6, lane = tid & 63;
  const int wm = wid >> 2, wn = wid & 3;
  const int l31 = lane & 31, kg5 = lane >> 5;

  int bid = blockIdx.x;
  const int qq = gridDim.x >> 3;
  bid = (bid & 7) * qq + (bid >> 3);        // XCD swizzle (grid % 8 == 0)
  const long row0 = (long)(bid / NTILE) * 256;
  const long col0 = (long)(bid % NTILE) * BN;

  const int srow = tid >> 2;                                   // 0..127
  const int sce = (((tid & 3) ^ ((srow >> 1) & 3)) << 3);      // pre-swizzled col
  const bf16_t* pA = A + (row0 + srow) * (long)K + sce;
  const bf16_t* pB = Bw + (col0 + srow) * (long)K + sce;
  char* ldsp = (char*)lds;

  auto SA = [&](int buf, int ks, int kt) {
    char* d_ = ldsp + buf * BUFB + ks * 16384 + tid * 16;
    const bf16_t* g_ = pA + (long)kt * 64 + ks * 32;
    gload_lds16(g_, d_);
    gload_lds16(g_ + 128L * K, d_ + 8192);
  };
  auto SB = [&](int buf, int ks, int kt) {
    char* d_ = ldsp + buf * BUFB + ABYT + ks * KSB + tid * 16;
    const bf16_t* g_ = pB + (long)kt * 64 + ks * 32;
    gload_lds16(g_, d_);
    if constexpr (BLOADS == 2) gload_lds16(g_ + 128L * K, d_ + 8192);
  };

  f32x16 acc[4][NF2] = {};
  bf16x8 af[4], bf[NF2];

  // fragment-read bases. swz = (l31>>1)&3 is lane-only (mf*32/nf*32 keep bits 1-2);
  // logical chunk (k16<<1|kg5) -> stored chunk ^swz; two per-thread chunk bytes.
  const int swz = (l31 >> 1) & 3;
  const int cb0 = (((0 << 1) | kg5) ^ swz) << 4;
  const int cb1 = (((1 << 1) | kg5) ^ swz) << 4;
  const char* aR = ldsp + (wm * 128 + l31) * 64;
  const char* bR = ldsp + ABYT + (wn * WNSPAN + l31) * 64;

  auto RD = [&](int buf, int ks, int k16) {
    const int cb = k16 ? cb1 : cb0;
    const char* a_ = aR + buf * BUFB + ks * 16384 + cb;
    const char* b_ = bR + buf * BUFB + ks * KSB + cb;
#pragma unroll
    for (int mf = 0; mf < 4; ++mf) af[mf] = *(const bf16x8*)(a_ + mf * 2048);
#pragma unroll
    for (int nf = 0; nf < NF2; ++nf) bf[nf] = *(const bf16x8*)(b_ + nf * 2048);
  };
  auto MM = [&]() {
    __builtin_amdgcn_s_setprio(1);
#pragma unroll
    for (int mf = 0; mf < 4; ++mf)
#pragma unroll
      for (int nf = 0; nf < NF2; ++nf)
        acc[mf][nf] =
            __builtin_amdgcn_mfma_f32_32x32x16_bf16(af[mf], bf[nf], acc[mf][nf], 0, 0, 0);
    __builtin_amdgcn_s_setprio(0);
  };
  auto W2U = [&]() {
    if constexpr (BLOADS == 2) asm volatile("s_waitcnt vmcnt(8)" ::: "memory");
    else                       asm volatile("s_waitcnt vmcnt(6)" ::: "memory");
  };
  auto W1U = [&]() {
    if constexpr (BLOADS == 2) asm volatile("s_waitcnt vmcnt(4)" ::: "memory");
    else                       asm volatile("s_waitcnt vmcnt(3)" ::: "memory");
  };
#define BARX() __builtin_amdgcn_s_barrier()
#define LGKM0() asm volatile("s_waitcnt lgkmcnt(0)" ::: "memory")
#define W0U() asm volatile("s_waitcnt vmcnt(0)" ::: "memory")

  // prologue: stage 3 units in consumption order; land unit 1 only
  SA(0, 0, 0); SB(0, 0, 0);
  SA(0, 1, 0); SB(0, 1, 0);
  SA(1, 0, 1); SB(1, 0, 1);
  W2U();
  BARX();

  for (int i = 0; i < NI; ++i) {
    const int t1 = 2 * i + 1, tA = 2 * i + 2, tB = 2 * i + 3;
    // p1: read b0.ks0.k0 | stage b1k1.A
    RD(0, 0, 0); SA(1, 1, t1);
    BARX(); LGKM0(); MM(); BARX();
    // p2: read b0.ks0.k1 | stage b1k1.B | wait lands b0k1 (for p3/p4)
    RD(0, 0, 1); SB(1, 1, t1);
    BARX(); LGKM0(); MM(); W2U(); BARX();
    // p3: read b0.ks1.k0 | stage next b0k0.A
    RD(0, 1, 0); if (tA < NT) SA(0, 0, tA);
    BARX(); LGKM0(); MM(); BARX();
    // p4: read b0.ks1.k1 | stage next b0k0.B | wait lands b1k0 (for p5/p6)
    RD(0, 1, 1); if (tA < NT) SB(0, 0, tA);
    BARX(); LGKM0(); MM();
    if (tA < NT) W2U(); else W1U();
    BARX();
    // p5: read b1.ks0.k0 | stage next b0k1.A
    RD(1, 0, 0); if (tA < NT) SA(0, 1, tA);
    BARX(); LGKM0(); MM(); BARX();
    // p6: read b1.ks0.k1 | stage next b0k1.B | wait lands b1k1 (for p7/p8)
    RD(1, 0, 1); if (tA < NT) SB(0, 1, tA);
    BARX(); LGKM0(); MM();
    if (tA < NT) W2U(); else W0U();
    BARX();
    // p7: read b1.ks1.k0 | stage next b1k0.A
    RD(1, 1, 0); if (tB < NT) SA(1, 0, tB);
    BARX(); LGKM0(); MM(); BARX();
    // p8: read b1.ks1.k1 | stage next b1k0.B | wait lands next b0k0
    RD(1, 1, 1); if (tB < NT) SB(1, 0, tB);
    BARX(); LGKM0(); MM();
    if (tB < NT) W2U();
    BARX();
  }
#undef BARX
#undef LGKM0
#undef W0U

  // epilogue: 32x32 C/D layout: col = l31, row = (r&3) + 8*(r>>2) + 4*kg5
  // GELU bf16 stores: 32 consecutive cols x 2B = full 64B sectors (no RMW amp).
#pragma unroll
  for (int mf = 0; mf < 4; ++mf) {
#pragma unroll
    for (int nf = 0; nf < NF2; ++nf) {
      const long col = col0 + wn * WNSPAN + nf * 32 + l31;
      const float bs = bias[col];
#pragma unroll
      for (int r = 0; r < 16; ++r) {
        const long row = row0 + wm * 128 + mf * 32 + (r & 3) + 8 * (r >> 2) + 4 * kg5;
        const float v = acc[mf][nf][r] + bs;
        if constexpr (GELU) {
          const float u = 0.7978845608028654f * (v + 0.044715f * v * v * v);
          const float gv = v / (1.f + __expf(-2.f * u));
          outb[row * NOUT + col] = (bf16_t)gv;
        } else {
          outf[row * NOUT + col] += v;   // residual RMW onto x2 already in d_out
        }
      }
    }
  }
}

extern "C" void kernel_launch(void* const* d_in, const int* in_sizes, int n_in,
                              void* d_out, int out_size, void* d_ws, size_t ws_size,
                              hipStream_t stream) {
  const float* x   = (const float*)d_in[0];
  const float* n1w = (const float*)d_in[2];
  const float* n1b = (const float*)d_in[3];
  const float* klw = (const float*)d_in[4];
  const float* klb = (const float*)d_in[5];
  const float* vlw = (const float*)d_in[6];
  const float* vlb = (const float*)d_in[7];
  const float* n2w = (const float*)d_in[8];
  const float* n2b = (const float*)d_in[9];
  const float* w1f = (const float*)d_in[10];
  const float* b1  = (const float*)d_in[11];
  const float* w2f = (const float*)d_in[12];
  const float* b2  = (const float*)d_in[13];
  float* out = (float*)d_out;

  // chunk count by available workspace (act = 256MiB/nch)
  int nch;
  if (ws_size >= 423755776ULL)      nch = 1;
  else if (ws_size >= 289538048ULL) nch = 2;
  else                              nch = 4;
  const long mch = MTOT / nch;

  char* ws = (char*)d_ws;
  size_t off = 0;
  bf16_t* h   = (bf16_t*)(ws + off); off += (size_t)MTOT * CC * 2;      // 64 MiB
  bf16_t* mb  = (bf16_t*)(ws + off); off += (size_t)MTOT * CC * 2;      // 64 MiB
  bf16_t* act = (bf16_t*)(ws + off); off += (size_t)mch * HID * 2;      // 256/nch MiB
  bf16_t* w1  = (bf16_t*)(ws + off); off += (size_t)HID * CC * 2;       // 2 MiB
  bf16_t* w2  = (bf16_t*)(ws + off); off += (size_t)HID * CC * 2;       // 2 MiB
  float*  kvp = (float*)(ws + off);  off += (size_t)BB * HH * 64 * 1024 * 4; // 16 MiB
  bf16_t* kvT = (bf16_t*)(ws + off);                                    // 128 KiB

  cvt_bf16_kernel<<<1024, 256, 0, stream>>>(w1f, w1);
  cvt_bf16_kernel<<<1024, 256, 0, stream>>>(w2f, w2);
  norm1_kernel<<<MTOT / 4, 256, 0, stream>>>(x, n1w, n1b, h);
  kv_partial_kernel<<<BB * HH * 64, 256, 0, stream>>>(h, klw, klb, vlw, vlb, kvp);
  kv_reduce_kernel<<<BB * HH, 256, 0, stream>>>(kvp, kvT);
  attn_fused_kernel<<<MTOT / 32, 256, 0, stream>>>(x, h, kvT, n2w, n2b, out, mb);
  for (int ch = 0; ch < nch; ++ch) {
    gemm8p_kernel<CC, HID, 256, true>
        <<<(int)((mch / 256) * (HID / 256)), 512, 0, stream>>>(
        mb + (size_t)ch * mch * CC, w1, b1, act, nullptr);
    if (mch >= 32768) {
      gemm8p_kernel<HID, CC, 256, false>
          <<<(int)((mch / 256) * (CC / 256)), 512, 0, stream>>>(
          act, w2, b2, nullptr, out + (size_t)ch * mch * CC);
    } else {
      gemm8p_kernel<HID, CC, 128, false>
          <<<(int)((mch / 256) * (CC / 128)), 512, 0, stream>>>(
          act, w2, b2, nullptr, out + (size_t)ch * mch * CC);
    }
  }
}

// Round 15
// 574.416 us; speedup vs baseline: 1.4253x; 1.0254x over previous
//
#include <hip/hip_runtime.h>
#include <cstdint>

// Problem constants
#define BB 4
#define NN 16384
#define CC 512
#define HH 16
#define DD 32
#define HID 2048
#define MTOT (BB * NN)        // 65536 tokens

typedef __bf16 bf16_t;
typedef __bf16 bf16x8 __attribute__((ext_vector_type(8)));
typedef __bf16 bf16x4 __attribute__((ext_vector_type(4)));
typedef float  f32x4  __attribute__((ext_vector_type(4)));
typedef float  f32x16 __attribute__((ext_vector_type(16)));

// ---- async global->LDS 16B ----
__device__ __forceinline__ void gload_lds16(const void* g, void* l) {
  auto gp = reinterpret_cast<const __attribute__((address_space(1))) char*>(
      reinterpret_cast<uintptr_t>(g));
  auto lp = reinterpret_cast<__attribute__((address_space(3))) char*>(
      reinterpret_cast<uintptr_t>(l));
  __builtin_amdgcn_global_load_lds(gp, lp, 16, 0, 0);
}

// ---- fp32 -> bf16 weight convert ----
__global__ __launch_bounds__(256) void cvt_bf16_kernel(const float* __restrict__ src,
                                                       bf16_t* __restrict__ dst) {
  const long i = ((long)blockIdx.x * 256 + threadIdx.x) * 4;
  const f32x4 v = *(const f32x4*)(src + i);
  bf16x4 o;
  o[0] = (bf16_t)v[0]; o[1] = (bf16_t)v[1]; o[2] = (bf16_t)v[2]; o[3] = (bf16_t)v[3];
  *(bf16x4*)(dst + i) = o;
}

// ---- LayerNorm1: one wave per token; lane owns 8 contiguous channels ----
__global__ __launch_bounds__(256) void norm1_kernel(const float* __restrict__ x,
                                                    const float* __restrict__ w,
                                                    const float* __restrict__ bvec,
                                                    bf16_t* __restrict__ h) {
  const int wv = threadIdx.x >> 6, l = threadIdx.x & 63;
  const long tok = (long)blockIdx.x * 4 + wv;
  const int c0 = l * 8;
  const f32x4 a = *(const f32x4*)(x + tok * CC + c0);
  const f32x4 b = *(const f32x4*)(x + tok * CC + c0 + 4);
  float v[8];
#pragma unroll
  for (int i = 0; i < 4; ++i) { v[i] = a[i]; v[4 + i] = b[i]; }
  float s = 0.f, s2 = 0.f;
#pragma unroll
  for (int i = 0; i < 8; ++i) { s += v[i]; s2 += v[i] * v[i]; }
  for (int off = 32; off; off >>= 1) { s += __shfl_xor(s, off); s2 += __shfl_xor(s2, off); }
  const float mean = s * (1.f / CC);
  const float var  = fmaxf(s2 * (1.f / CC) - mean * mean, 0.f);
  const float rstd = rsqrtf(var + 1e-5f);
  const f32x4 w0 = *(const f32x4*)(w + c0), w1 = *(const f32x4*)(w + c0 + 4);
  const f32x4 b0 = *(const f32x4*)(bvec + c0), b1 = *(const f32x4*)(bvec + c0 + 4);
  bf16x8 o;
#pragma unroll
  for (int i = 0; i < 4; ++i) {
    o[i]     = (bf16_t)(w0[i] * (v[i] - mean) * rstd + b0[i]);
    o[4 + i] = (bf16_t)(w1[i] * (v[4 + i] - mean) * rstd + b1[i]);
  }
  *(bf16x8*)(h + tok * CC + c0) = o;
}

// ---- kv partial: block = (b,head,chunk of 256 tokens) ----
__global__ __launch_bounds__(256) void kv_partial_kernel(const bf16_t* __restrict__ h,
                                                         const float* __restrict__ klw,
                                                         const float* __restrict__ klb,
                                                         const float* __restrict__ vlw,
                                                         const float* __restrict__ vlb,
                                                         float* __restrict__ kvp) {
  __shared__ bf16_t kb[256 * 32];
  __shared__ bf16_t vb[256 * 32];
  __shared__ float scratch[192 * 16];   // 12KB
  const int tid = threadIdx.x;
  const int bh = blockIdx.x >> 6, chunk = blockIdx.x & 63;
  const int head = bh & 15;
  const int b = bh >> 4;
  const long tok0 = ((long)b << 14) + chunk * 256;
  const bf16_t* src = h + (tok0 + tid) * (long)CC + head * DD;
  float hv[32];
  {
    float s = 0.f, s2 = 0.f;
#pragma unroll
    for (int c = 0; c < 4; ++c) {
      const bf16x8 r = *(const bf16x8*)(src + c * 8);
#pragma unroll
      for (int j = 0; j < 8; ++j) {
        hv[c * 8 + j] = (float)r[j]; s += hv[c * 8 + j]; s2 += hv[c * 8 + j] * hv[c * 8 + j];
      }
    }
    const float mean = s * (1.f / 32.f);
    const float varu = fmaxf((s2 - 32.f * mean * mean) * (1.f / 31.f), 0.f);
    const float inv = 1.f / (sqrtf(varu) + 1e-5f);   // torch.std semantics
    const int sx = (tid >> 1) & 3;
#pragma unroll
    for (int c = 0; c < 4; ++c) {
      bf16x8 kc, vc;
#pragma unroll
      for (int j = 0; j < 8; ++j) {
        const int d = c * 8 + j;
        const float t = (hv[d] - mean) * inv;
        kc[j] = (bf16_t)(klw[head * DD + d] * t + klb[head * DD + d]);
        vc[j] = (bf16_t)(vlw[head * DD + d] * t + vlb[head * DD + d]);
      }
      *(bf16x8*)((char*)kb + tid * 64 + ((c ^ sx) * 16)) = kc;
      *(bf16x8*)((char*)vb + tid * 64 + ((c ^ sx) * 16)) = vc;
    }
  }
  __syncthreads();
  const int g = tid >> 6, l = tid & 63;
  const int d0 = (l >> 3) * 4, e0 = (l & 7) * 4;
  const int ck = (l >> 3) >> 1, hk = (l >> 3) & 1;
  const int ce = (l & 7) >> 1, he = l & 1;
  float a[4][4] = {};
  for (int t = g; t < 256; t += 4) {
    const int tx = (t >> 1) & 3;
    const bf16x4 kq = *(const bf16x4*)((const char*)kb + t * 64 + ((ck ^ tx) * 16) + hk * 8);
    const bf16x4 vq = *(const bf16x4*)((const char*)vb + t * 64 + ((ce ^ tx) * 16) + he * 8);
    float kf[4], vf[4];
#pragma unroll
    for (int i2 = 0; i2 < 4; ++i2) { kf[i2] = (float)kq[i2]; vf[i2] = (float)vq[i2]; }
#pragma unroll
    for (int i2 = 0; i2 < 4; ++i2)
#pragma unroll
      for (int j2 = 0; j2 < 4; ++j2) a[i2][j2] += kf[i2] * vf[j2];
  }
  __syncthreads();
  if (g) {
#pragma unroll
    for (int i2 = 0; i2 < 4; ++i2)
#pragma unroll
      for (int j2 = 0; j2 < 4; ++j2)
        scratch[((g - 1) * 64 + l) * 16 + i2 * 4 + j2] = a[i2][j2];
  }
  __syncthreads();
  if (!g) {
#pragma unroll
    for (int gg = 0; gg < 3; ++gg)
#pragma unroll
      for (int i2 = 0; i2 < 4; ++i2)
#pragma unroll
        for (int j2 = 0; j2 < 4; ++j2)
          a[i2][j2] += scratch[(gg * 64 + l) * 16 + i2 * 4 + j2];
    float* dst = kvp + ((long)(bh * 64 + chunk) << 10);
#pragma unroll
    for (int i2 = 0; i2 < 4; ++i2) {
      f32x4 st;
      st[0] = a[i2][0]; st[1] = a[i2][1]; st[2] = a[i2][2]; st[3] = a[i2][3];
      *(f32x4*)&dst[(d0 + i2) * 32 + e0] = st;
    }
  }
}

// ---- kv reduce over 64 chunks, /N, store TRANSPOSED bf16: kvT[bh][e][d] ----
__global__ __launch_bounds__(256) void kv_reduce_kernel(const float* __restrict__ kvp,
                                                        bf16_t* __restrict__ kvT) {
  const int bh = blockIdx.x;
  const int i4 = threadIdx.x * 4;
  const int d = i4 >> 5, e0 = i4 & 31;
  float s[4] = {};
  const float* p = kvp + ((long)bh << 16) + i4;
  for (int ch = 0; ch < 64; ++ch) {
    const f32x4 t = *(const f32x4*)(p + (ch << 10));
    s[0] += t[0]; s[1] += t[1]; s[2] += t[2]; s[3] += t[3];
  }
  const float sc = 1.f / (float)NN;
  bf16_t* q = kvT + ((long)bh << 10);
#pragma unroll
  for (int j = 0; j < 4; ++j) q[(e0 + j) * 32 + d] = (bf16_t)(s[j] * sc);
}

// ---- fused: MFMA attn + residuals -> x2 (bf16 to ws), LN2 -> m (bf16) ----
#define ASTRIDE 520
__global__ __launch_bounds__(256) void attn_fused_kernel(const float* __restrict__ x,
                                                         const bf16_t* __restrict__ h,
                                                         const bf16_t* __restrict__ kvTg,
                                                         const float* __restrict__ n2w,
                                                         const float* __restrict__ n2b,
                                                         bf16_t* __restrict__ x2b,
                                                         bf16_t* __restrict__ mout) {
  __shared__ bf16_t attn_s[32 * ASTRIDE];
  const int tid = threadIdx.x;
  const int wv = tid >> 6, lane = tid & 63;
  const int lr = lane & 15, kg = lane >> 4;
  const long tok0 = (long)blockIdx.x * 32;
  const int b = (int)(tok0 >> 14);
  const bf16_t* kvsrc = kvTg + ((long)b << 14);

  {
    const int tt = wv & 1, hh = wv >> 1;
    const bf16_t* arow = h + (tok0 + tt * 16 + lr) * (long)CC + kg * 8;
    const f32x4 zero = {};
#pragma unroll
    for (int hi = 0; hi < 8; ++hi) {
      const int hd = hh * 8 + hi;
      const bf16_t* kvh = kvsrc + (hd << 10) + kg * 8;
      const bf16x8 af = *(const bf16x8*)(arow + hd * DD);
      const bf16x8 b0 = *(const bf16x8*)(kvh + lr * 32);
      const bf16x8 b1 = *(const bf16x8*)(kvh + (16 + lr) * 32);
      const f32x4 a0 = __builtin_amdgcn_mfma_f32_16x16x32_bf16(af, b0, zero, 0, 0, 0);
      const f32x4 a1 = __builtin_amdgcn_mfma_f32_16x16x32_bf16(af, b1, zero, 0, 0, 0);
      const int rbase = tt * 16 + kg * 4;
#pragma unroll
      for (int rg = 0; rg < 4; ++rg) {
        attn_s[(rbase + rg) * ASTRIDE + hd * 32 + lr]      = (bf16_t)a0[rg];
        attn_s[(rbase + rg) * ASTRIDE + hd * 32 + 16 + lr] = (bf16_t)a1[rg];
      }
    }
  }

  const int c0 = lane * 8;
  const f32x4 w0 = *(const f32x4*)(n2w + c0), w1 = *(const f32x4*)(n2w + c0 + 4);
  const f32x4 bb0 = *(const f32x4*)(n2b + c0), bb1 = *(const f32x4*)(n2b + c0 + 4);

  // preload it=0 BEFORE the barrier (independent of attn_s)
  const long tokp = tok0 + wv * 8;
  f32x4 xa = *(const f32x4*)(x + tokp * CC + c0);
  f32x4 xb = *(const f32x4*)(x + tokp * CC + c0 + 4);
  bf16x8 hv = *(const bf16x8*)(h + tokp * CC + c0);
  __syncthreads();

#pragma unroll
  for (int it = 0; it < 8; ++it) {
    const int tl = wv * 8 + it;
    const long tok = tok0 + tl;
    f32x4 xa1, xb1;
    bf16x8 hv1;
    if (it < 7) {
      xa1 = *(const f32x4*)(x + (tok + 1) * CC + c0);
      xb1 = *(const f32x4*)(x + (tok + 1) * CC + c0 + 4);
      hv1 = *(const bf16x8*)(h + (tok + 1) * CC + c0);
    }
    const bf16x8 av = *(const bf16x8*)&attn_s[tl * ASTRIDE + c0];
    float x2[8];
#pragma unroll
    for (int i = 0; i < 4; ++i) {
      x2[i]     = xa[i] + (float)hv[i]     + (float)av[i];
      x2[4 + i] = xb[i] + (float)hv[4 + i] + (float)av[4 + i];
    }
    float s = 0.f, s2 = 0.f;
#pragma unroll
    for (int i = 0; i < 8; ++i) { s += x2[i]; s2 += x2[i] * x2[i]; }
    for (int off = 32; off; off >>= 1) { s += __shfl_xor(s, off); s2 += __shfl_xor(s2, off); }
    const float mean = s * (1.f / CC);
    const float var  = fmaxf(s2 * (1.f / CC) - mean * mean, 0.f);
    const float rstd = rsqrtf(var + 1e-5f);
    bf16x8 ox, om;
#pragma unroll
    for (int i = 0; i < 4; ++i) {
      ox[i]     = (bf16_t)x2[i];
      ox[4 + i] = (bf16_t)x2[4 + i];
      om[i]     = (bf16_t)(w0[i] * (x2[i] - mean) * rstd + bb0[i]);
      om[4 + i] = (bf16_t)(w1[i] * (x2[4 + i] - mean) * rstd + bb1[i]);
    }
    *(bf16x8*)(x2b + tok * CC + c0) = ox;
    *(bf16x8*)(mout + tok * CC + c0) = om;
    xa = xa1; xb = xb1; hv = hv1;
  }
}

// ---- 8-phase GEMM (r6 schedule) with 32x32x16 MFMA ----
// Swizzle enriched: swz(row) = ((row>>1)&3) ^ ((row>>3)&3), applied to staging
// source col and fragment reads (lane-only for reads; bases are 32-multiples).
// GELU=false epilogue: pure store out = x2b + acc + bias (no fp32 RMW read).
template <int K, int NOUT, int BN, bool GELU>
__global__ __launch_bounds__(512, 2) void gemm8p_kernel(const bf16_t* __restrict__ A,
                                                        const bf16_t* __restrict__ Bw,
                                                        const float* __restrict__ bias,
                                                        bf16_t* __restrict__ outb,
                                                        float* __restrict__ outf,
                                                        const bf16_t* __restrict__ x2b) {
  constexpr int NTILE = NOUT / BN;
  constexpr int NT = K / 64;                 // K-tiles
  constexpr int NI = NT / 2;                 // iterations (2 K-tiles each)
  constexpr int WNSPAN = BN / 4;             // wave N span (64 or 32)
  constexpr int NF2 = WNSPAN / 32;           // 32-wide N frags per wave (2 or 1)
  constexpr int BLOADS = BN / 128;           // B loads per ks-unit (2 or 1)
  constexpr int ABYT = 32768;                // A bytes per buffer
  constexpr int BBYT = BN * 128;             // B bytes per buffer
  constexpr int BUFB = ABYT + BBYT;
  constexpr int KSB = BN * 64;               // B kslice stride (bytes)

  __shared__ char lds[2 * BUFB];

  const int tid = threadIdx.x;
  const int wid = tid >> 6, lane = tid & 63;
  const int wm = wid >> 2, wn = wid & 3;
  const int l31 = lane & 31, kg5 = lane >> 5;

  int bid = blockIdx.x;
  const int qq = gridDim.x >> 3;
  bid = (bid & 7) * qq + (bid >> 3);        // XCD swizzle (grid % 8 == 0)
  const long row0 = (long)(bid / NTILE) * 256;
  const long col0 = (long)(bid % NTILE) * BN;

  const int srow = tid >> 2;                                   // 0..127
  const int ssw = (((srow >> 1) & 3) ^ ((srow >> 3) & 3));     // enriched swizzle
  const int sce = (((tid & 3) ^ ssw) << 3);                    // pre-swizzled col
  const bf16_t* pA = A + (row0 + srow) * (long)K + sce;
  const bf16_t* pB = Bw + (col0 + srow) * (long)K + sce;
  char* ldsp = (char*)lds;

  auto SA = [&](int buf, int ks, int kt) {
    char* d_ = ldsp + buf * BUFB + ks * 16384 + tid * 16;
    const bf16_t* g_ = pA + (long)kt * 64 + ks * 32;
    gload_lds16(g_, d_);
    gload_lds16(g_ + 128L * K, d_ + 8192);
  };
  auto SB = [&](int buf, int ks, int kt) {
    char* d_ = ldsp + buf * BUFB + ABYT + ks * KSB + tid * 16;
    const bf16_t* g_ = pB + (long)kt * 64 + ks * 32;
    gload_lds16(g_, d_);
    if constexpr (BLOADS == 2) gload_lds16(g_ + 128L * K, d_ + 8192);
  };

  f32x16 acc[4][NF2] = {};
  bf16x8 af[4], bf[NF2];

  // fragment-read bases. swz = ((l31>>1)&3)^((l31>>3)&3) is lane-only
  // (mf*32/nf*32 bases keep row bits 1-4); chunk (k16<<1|kg5) -> stored ^swz.
  const int swz = ((l31 >> 1) & 3) ^ ((l31 >> 3) & 3);
  const int cb0 = (((0 << 1) | kg5) ^ swz) << 4;
  const int cb1 = (((1 << 1) | kg5) ^ swz) << 4;
  const char* aR = ldsp + (wm * 128 + l31) * 64;
  const char* bR = ldsp + ABYT + (wn * WNSPAN + l31) * 64;

  auto RD = [&](int buf, int ks, int k16) {
    const int cb = k16 ? cb1 : cb0;
    const char* a_ = aR + buf * BUFB + ks * 16384 + cb;
    const char* b_ = bR + buf * BUFB + ks * KSB + cb;
#pragma unroll
    for (int mf = 0; mf < 4; ++mf) af[mf] = *(const bf16x8*)(a_ + mf * 2048);
#pragma unroll
    for (int nf = 0; nf < NF2; ++nf) bf[nf] = *(const bf16x8*)(b_ + nf * 2048);
  };
  auto MM = [&]() {
    __builtin_amdgcn_s_setprio(1);
#pragma unroll
    for (int mf = 0; mf < 4; ++mf)
#pragma unroll
      for (int nf = 0; nf < NF2; ++nf)
        acc[mf][nf] =
            __builtin_amdgcn_mfma_f32_32x32x16_bf16(af[mf], bf[nf], acc[mf][nf], 0, 0, 0);
    __builtin_amdgcn_s_setprio(0);
  };
  auto W2U = [&]() {
    if constexpr (BLOADS == 2) asm volatile("s_waitcnt vmcnt(8)" ::: "memory");
    else                       asm volatile("s_waitcnt vmcnt(6)" ::: "memory");
  };
  auto W1U = [&]() {
    if constexpr (BLOADS == 2) asm volatile("s_waitcnt vmcnt(4)" ::: "memory");
    else                       asm volatile("s_waitcnt vmcnt(3)" ::: "memory");
  };
#define BARX() __builtin_amdgcn_s_barrier()
#define LGKM0() asm volatile("s_waitcnt lgkmcnt(0)" ::: "memory")
#define W0U() asm volatile("s_waitcnt vmcnt(0)" ::: "memory")

  // prologue: stage 3 units in consumption order; land unit 1 only
  SA(0, 0, 0); SB(0, 0, 0);
  SA(0, 1, 0); SB(0, 1, 0);
  SA(1, 0, 1); SB(1, 0, 1);
  W2U();
  BARX();

  for (int i = 0; i < NI; ++i) {
    const int t1 = 2 * i + 1, tA = 2 * i + 2, tB = 2 * i + 3;
    // p1: read b0.ks0.k0 | stage b1k1.A
    RD(0, 0, 0); SA(1, 1, t1);
    BARX(); LGKM0(); MM(); BARX();
    // p2: read b0.ks0.k1 | stage b1k1.B | wait lands b0k1 (for p3/p4)
    RD(0, 0, 1); SB(1, 1, t1);
    BARX(); LGKM0(); MM(); W2U(); BARX();
    // p3: read b0.ks1.k0 | stage next b0k0.A
    RD(0, 1, 0); if (tA < NT) SA(0, 0, tA);
    BARX(); LGKM0(); MM(); BARX();
    // p4: read b0.ks1.k1 | stage next b0k0.B | wait lands b1k0 (for p5/p6)
    RD(0, 1, 1); if (tA < NT) SB(0, 0, tA);
    BARX(); LGKM0(); MM();
    if (tA < NT) W2U(); else W1U();
    BARX();
    // p5: read b1.ks0.k0 | stage next b0k1.A
    RD(1, 0, 0); if (tA < NT) SA(0, 1, tA);
    BARX(); LGKM0(); MM(); BARX();
    // p6: read b1.ks0.k1 | stage next b0k1.B | wait lands b1k1 (for p7/p8)
    RD(1, 0, 1); if (tA < NT) SB(0, 1, tA);
    BARX(); LGKM0(); MM();
    if (tA < NT) W2U(); else W0U();
    BARX();
    // p7: read b1.ks1.k0 | stage next b1k0.A
    RD(1, 1, 0); if (tB < NT) SA(1, 0, tB);
    BARX(); LGKM0(); MM(); BARX();
    // p8: read b1.ks1.k1 | stage next b1k0.B | wait lands next b0k0
    RD(1, 1, 1); if (tB < NT) SB(1, 0, tB);
    BARX(); LGKM0(); MM();
    if (tB < NT) W2U();
    BARX();
  }
#undef BARX
#undef LGKM0
#undef W0U

  // epilogue: 32x32 C/D layout: col = l31, row = (r&3) + 8*(r>>2) + 4*kg5
#pragma unroll
  for (int mf = 0; mf < 4; ++mf) {
#pragma unroll
    for (int nf = 0; nf < NF2; ++nf) {
      const long col = col0 + wn * WNSPAN + nf * 32 + l31;
      const float bs = bias[col];
#pragma unroll
      for (int r = 0; r < 16; ++r) {
        const long row = row0 + wm * 128 + mf * 32 + (r & 3) + 8 * (r >> 2) + 4 * kg5;
        const float v = acc[mf][nf][r] + bs;
        if constexpr (GELU) {
          const float u = 0.7978845608028654f * (v + 0.044715f * v * v * v);
          const float gv = v / (1.f + __expf(-2.f * u));
          outb[row * NOUT + col] = (bf16_t)gv;
        } else {
          // pure store: final out = x2 + mlp (x2 read back as bf16 from ws)
          outf[row * NOUT + col] = (float)x2b[row * NOUT + col] + v;
        }
      }
    }
  }
}

extern "C" void kernel_launch(void* const* d_in, const int* in_sizes, int n_in,
                              void* d_out, int out_size, void* d_ws, size_t ws_size,
                              hipStream_t stream) {
  const float* x   = (const float*)d_in[0];
  const float* n1w = (const float*)d_in[2];
  const float* n1b = (const float*)d_in[3];
  const float* klw = (const float*)d_in[4];
  const float* klb = (const float*)d_in[5];
  const float* vlw = (const float*)d_in[6];
  const float* vlb = (const float*)d_in[7];
  const float* n2w = (const float*)d_in[8];
  const float* n2b = (const float*)d_in[9];
  const float* w1f = (const float*)d_in[10];
  const float* b1  = (const float*)d_in[11];
  const float* w2f = (const float*)d_in[12];
  const float* b2  = (const float*)d_in[13];
  float* out = (float*)d_out;

  // nch=2: act chunk = 128MB -> L3-resident between GEMM1 and GEMM2
  int nch;
  if (ws_size >= 360000000ULL) nch = 2;
  else                         nch = 4;
  const long mch = MTOT / nch;

  char* ws = (char*)d_ws;
  size_t off = 0;
  bf16_t* h   = (bf16_t*)(ws + off); off += (size_t)MTOT * CC * 2;      // 64 MiB
  bf16_t* mb  = (bf16_t*)(ws + off); off += (size_t)MTOT * CC * 2;      // 64 MiB
  bf16_t* x2b = (bf16_t*)(ws + off); off += (size_t)MTOT * CC * 2;      // 64 MiB
  bf16_t* act = (bf16_t*)(ws + off); off += (size_t)mch * HID * 2;      // 256/nch MiB
  bf16_t* w1  = (bf16_t*)(ws + off); off += (size_t)HID * CC * 2;       // 2 MiB
  bf16_t* w2  = (bf16_t*)(ws + off); off += (size_t)HID * CC * 2;       // 2 MiB
  float*  kvp = (float*)(ws + off);  off += (size_t)BB * HH * 64 * 1024 * 4; // 16 MiB
  bf16_t* kvT = (bf16_t*)(ws + off);                                    // 128 KiB

  cvt_bf16_kernel<<<1024, 256, 0, stream>>>(w1f, w1);
  cvt_bf16_kernel<<<1024, 256, 0, stream>>>(w2f, w2);
  norm1_kernel<<<MTOT / 4, 256, 0, stream>>>(x, n1w, n1b, h);
  kv_partial_kernel<<<BB * HH * 64, 256, 0, stream>>>(h, klw, klb, vlw, vlb, kvp);
  kv_reduce_kernel<<<BB * HH, 256, 0, stream>>>(kvp, kvT);
  attn_fused_kernel<<<MTOT / 32, 256, 0, stream>>>(x, h, kvT, n2w, n2b, x2b, mb);
  for (int ch = 0; ch < nch; ++ch) {
    gemm8p_kernel<CC, HID, 256, true>
        <<<(int)((mch / 256) * (HID / 256)), 512, 0, stream>>>(
        mb + (size_t)ch * mch * CC, w1, b1, act, nullptr, nullptr);
    if (mch >= 32768) {
      gemm8p_kernel<HID, CC, 256, false>
          <<<(int)((mch / 256) * (CC / 256)), 512, 0, stream>>>(
          act, w2, b2, nullptr, out + (size_t)ch * mch * CC,
          x2b + (size_t)ch * mch * CC);
    } else {
      gemm8p_kernel<HID, CC, 128, false>
          <<<(int)((mch / 256) * (CC / 128)), 512, 0, stream>>>(
          act, w2, b2, nullptr, out + (size_t)ch * mch * CC,
          x2b + (size_t)ch * mch * CC);
    }
  }
}

// Round 16
// 572.900 us; speedup vs baseline: 1.4291x; 1.0026x over previous
//
#include <hip/hip_runtime.h>
#include <cstdint>

// Problem constants
#define BB 4
#define NN 16384
#define CC 512
#define HH 16
#define DD 32
#define HID 2048
#define MTOT (BB * NN)        // 65536 tokens

typedef __bf16 bf16_t;
typedef __bf16 bf16x8 __attribute__((ext_vector_type(8)));
typedef __bf16 bf16x4 __attribute__((ext_vector_type(4)));
typedef float  f32x4  __attribute__((ext_vector_type(4)));
typedef float  f32x16 __attribute__((ext_vector_type(16)));

// ---- async global->LDS 16B ----
__device__ __forceinline__ void gload_lds16(const void* g, void* l) {
  auto gp = reinterpret_cast<const __attribute__((address_space(1))) char*>(
      reinterpret_cast<uintptr_t>(g));
  auto lp = reinterpret_cast<__attribute__((address_space(3))) char*>(
      reinterpret_cast<uintptr_t>(l));
  __builtin_amdgcn_global_load_lds(gp, lp, 16, 0, 0);
}

// ---- fp32 -> bf16 weight convert ----
__global__ __launch_bounds__(256) void cvt_bf16_kernel(const float* __restrict__ src,
                                                       bf16_t* __restrict__ dst) {
  const long i = ((long)blockIdx.x * 256 + threadIdx.x) * 4;
  const f32x4 v = *(const f32x4*)(src + i);
  bf16x4 o;
  o[0] = (bf16_t)v[0]; o[1] = (bf16_t)v[1]; o[2] = (bf16_t)v[2]; o[3] = (bf16_t)v[3];
  *(bf16x4*)(dst + i) = o;
}

// ---- LayerNorm1: one wave per token; lane owns 8 contiguous channels ----
__global__ __launch_bounds__(256) void norm1_kernel(const float* __restrict__ x,
                                                    const float* __restrict__ w,
                                                    const float* __restrict__ bvec,
                                                    bf16_t* __restrict__ h) {
  const int wv = threadIdx.x >> 6, l = threadIdx.x & 63;
  const long tok = (long)blockIdx.x * 4 + wv;
  const int c0 = l * 8;
  const f32x4 a = *(const f32x4*)(x + tok * CC + c0);
  const f32x4 b = *(const f32x4*)(x + tok * CC + c0 + 4);
  float v[8];
#pragma unroll
  for (int i = 0; i < 4; ++i) { v[i] = a[i]; v[4 + i] = b[i]; }
  float s = 0.f, s2 = 0.f;
#pragma unroll
  for (int i = 0; i < 8; ++i) { s += v[i]; s2 += v[i] * v[i]; }
  for (int off = 32; off; off >>= 1) { s += __shfl_xor(s, off); s2 += __shfl_xor(s2, off); }
  const float mean = s * (1.f / CC);
  const float var  = fmaxf(s2 * (1.f / CC) - mean * mean, 0.f);
  const float rstd = rsqrtf(var + 1e-5f);
  const f32x4 w0 = *(const f32x4*)(w + c0), w1 = *(const f32x4*)(w + c0 + 4);
  const f32x4 b0 = *(const f32x4*)(bvec + c0), b1 = *(const f32x4*)(bvec + c0 + 4);
  bf16x8 o;
#pragma unroll
  for (int i = 0; i < 4; ++i) {
    o[i]     = (bf16_t)(w0[i] * (v[i] - mean) * rstd + b0[i]);
    o[4 + i] = (bf16_t)(w1[i] * (v[4 + i] - mean) * rstd + b1[i]);
  }
  *(bf16x8*)(h + tok * CC + c0) = o;
}

// ---- kv partial: block = (b,head,chunk of 256 tokens) ----
__global__ __launch_bounds__(256) void kv_partial_kernel(const bf16_t* __restrict__ h,
                                                         const float* __restrict__ klw,
                                                         const float* __restrict__ klb,
                                                         const float* __restrict__ vlw,
                                                         const float* __restrict__ vlb,
                                                         float* __restrict__ kvp) {
  __shared__ bf16_t kb[256 * 32];
  __shared__ bf16_t vb[256 * 32];
  __shared__ float scratch[192 * 16];   // 12KB
  const int tid = threadIdx.x;
  const int bh = blockIdx.x >> 6, chunk = blockIdx.x & 63;
  const int head = bh & 15;
  const int b = bh >> 4;
  const long tok0 = ((long)b << 14) + chunk * 256;
  const bf16_t* src = h + (tok0 + tid) * (long)CC + head * DD;
  float hv[32];
  {
    float s = 0.f, s2 = 0.f;
#pragma unroll
    for (int c = 0; c < 4; ++c) {
      const bf16x8 r = *(const bf16x8*)(src + c * 8);
#pragma unroll
      for (int j = 0; j < 8; ++j) {
        hv[c * 8 + j] = (float)r[j]; s += hv[c * 8 + j]; s2 += hv[c * 8 + j] * hv[c * 8 + j];
      }
    }
    const float mean = s * (1.f / 32.f);
    const float varu = fmaxf((s2 - 32.f * mean * mean) * (1.f / 31.f), 0.f);
    const float inv = 1.f / (sqrtf(varu) + 1e-5f);   // torch.std semantics
    const int sx = (tid >> 1) & 3;
#pragma unroll
    for (int c = 0; c < 4; ++c) {
      bf16x8 kc, vc;
#pragma unroll
      for (int j = 0; j < 8; ++j) {
        const int d = c * 8 + j;
        const float t = (hv[d] - mean) * inv;
        kc[j] = (bf16_t)(klw[head * DD + d] * t + klb[head * DD + d]);
        vc[j] = (bf16_t)(vlw[head * DD + d] * t + vlb[head * DD + d]);
      }
      *(bf16x8*)((char*)kb + tid * 64 + ((c ^ sx) * 16)) = kc;
      *(bf16x8*)((char*)vb + tid * 64 + ((c ^ sx) * 16)) = vc;
    }
  }
  __syncthreads();
  const int g = tid >> 6, l = tid & 63;
  const int d0 = (l >> 3) * 4, e0 = (l & 7) * 4;
  const int ck = (l >> 3) >> 1, hk = (l >> 3) & 1;
  const int ce = (l & 7) >> 1, he = l & 1;
  float a[4][4] = {};
  for (int t = g; t < 256; t += 4) {
    const int tx = (t >> 1) & 3;
    const bf16x4 kq = *(const bf16x4*)((const char*)kb + t * 64 + ((ck ^ tx) * 16) + hk * 8);
    const bf16x4 vq = *(const bf16x4*)((const char*)vb + t * 64 + ((ce ^ tx) * 16) + he * 8);
    float kf[4], vf[4];
#pragma unroll
    for (int i2 = 0; i2 < 4; ++i2) { kf[i2] = (float)kq[i2]; vf[i2] = (float)vq[i2]; }
#pragma unroll
    for (int i2 = 0; i2 < 4; ++i2)
#pragma unroll
      for (int j2 = 0; j2 < 4; ++j2) a[i2][j2] += kf[i2] * vf[j2];
  }
  __syncthreads();
  if (g) {
#pragma unroll
    for (int i2 = 0; i2 < 4; ++i2)
#pragma unroll
      for (int j2 = 0; j2 < 4; ++j2)
        scratch[((g - 1) * 64 + l) * 16 + i2 * 4 + j2] = a[i2][j2];
  }
  __syncthreads();
  if (!g) {
#pragma unroll
    for (int gg = 0; gg < 3; ++gg)
#pragma unroll
      for (int i2 = 0; i2 < 4; ++i2)
#pragma unroll
        for (int j2 = 0; j2 < 4; ++j2)
          a[i2][j2] += scratch[(gg * 64 + l) * 16 + i2 * 4 + j2];
    float* dst = kvp + ((long)(bh * 64 + chunk) << 10);
#pragma unroll
    for (int i2 = 0; i2 < 4; ++i2) {
      f32x4 st;
      st[0] = a[i2][0]; st[1] = a[i2][1]; st[2] = a[i2][2]; st[3] = a[i2][3];
      *(f32x4*)&dst[(d0 + i2) * 32 + e0] = st;
    }
  }
}

// ---- kv reduce over 64 chunks, /N, store TRANSPOSED bf16: kvT[bh][e][d] ----
__global__ __launch_bounds__(256) void kv_reduce_kernel(const float* __restrict__ kvp,
                                                        bf16_t* __restrict__ kvT) {
  const int bh = blockIdx.x;
  const int i4 = threadIdx.x * 4;
  const int d = i4 >> 5, e0 = i4 & 31;
  float s[4] = {};
  const float* p = kvp + ((long)bh << 16) + i4;
  for (int ch = 0; ch < 64; ++ch) {
    const f32x4 t = *(const f32x4*)(p + (ch << 10));
    s[0] += t[0]; s[1] += t[1]; s[2] += t[2]; s[3] += t[3];
  }
  const float sc = 1.f / (float)NN;
  bf16_t* q = kvT + ((long)bh << 10);
#pragma unroll
  for (int j = 0; j < 4; ++j) q[(e0 + j) * 32 + d] = (bf16_t)(s[j] * sc);
}

// ---- fused: MFMA attn + residuals -> x2 (bf16 to ws), LN2 -> m (bf16) ----
#define ASTRIDE 520
__global__ __launch_bounds__(256) void attn_fused_kernel(const float* __restrict__ x,
                                                         const bf16_t* __restrict__ h,
                                                         const bf16_t* __restrict__ kvTg,
                                                         const float* __restrict__ n2w,
                                                         const float* __restrict__ n2b,
                                                         bf16_t* __restrict__ x2b,
                                                         bf16_t* __restrict__ mout) {
  __shared__ bf16_t attn_s[32 * ASTRIDE];
  const int tid = threadIdx.x;
  const int wv = tid >> 6, lane = tid & 63;
  const int lr = lane & 15, kg = lane >> 4;
  const long tok0 = (long)blockIdx.x * 32;
  const int b = (int)(tok0 >> 14);
  const bf16_t* kvsrc = kvTg + ((long)b << 14);

  {
    const int tt = wv & 1, hh = wv >> 1;
    const bf16_t* arow = h + (tok0 + tt * 16 + lr) * (long)CC + kg * 8;
    const f32x4 zero = {};
#pragma unroll
    for (int hi = 0; hi < 8; ++hi) {
      const int hd = hh * 8 + hi;
      const bf16_t* kvh = kvsrc + (hd << 10) + kg * 8;
      const bf16x8 af = *(const bf16x8*)(arow + hd * DD);
      const bf16x8 b0 = *(const bf16x8*)(kvh + lr * 32);
      const bf16x8 b1 = *(const bf16x8*)(kvh + (16 + lr) * 32);
      const f32x4 a0 = __builtin_amdgcn_mfma_f32_16x16x32_bf16(af, b0, zero, 0, 0, 0);
      const f32x4 a1 = __builtin_amdgcn_mfma_f32_16x16x32_bf16(af, b1, zero, 0, 0, 0);
      const int rbase = tt * 16 + kg * 4;
#pragma unroll
      for (int rg = 0; rg < 4; ++rg) {
        attn_s[(rbase + rg) * ASTRIDE + hd * 32 + lr]      = (bf16_t)a0[rg];
        attn_s[(rbase + rg) * ASTRIDE + hd * 32 + 16 + lr] = (bf16_t)a1[rg];
      }
    }
  }

  const int c0 = lane * 8;
  const f32x4 w0 = *(const f32x4*)(n2w + c0), w1 = *(const f32x4*)(n2w + c0 + 4);
  const f32x4 bb0 = *(const f32x4*)(n2b + c0), bb1 = *(const f32x4*)(n2b + c0 + 4);

  // preload it=0 BEFORE the barrier (independent of attn_s)
  const long tokp = tok0 + wv * 8;
  f32x4 xa = *(const f32x4*)(x + tokp * CC + c0);
  f32x4 xb = *(const f32x4*)(x + tokp * CC + c0 + 4);
  bf16x8 hv = *(const bf16x8*)(h + tokp * CC + c0);
  __syncthreads();

#pragma unroll
  for (int it = 0; it < 8; ++it) {
    const int tl = wv * 8 + it;
    const long tok = tok0 + tl;
    f32x4 xa1, xb1;
    bf16x8 hv1;
    if (it < 7) {
      xa1 = *(const f32x4*)(x + (tok + 1) * CC + c0);
      xb1 = *(const f32x4*)(x + (tok + 1) * CC + c0 + 4);
      hv1 = *(const bf16x8*)(h + (tok + 1) * CC + c0);
    }
    const bf16x8 av = *(const bf16x8*)&attn_s[tl * ASTRIDE + c0];
    float x2[8];
#pragma unroll
    for (int i = 0; i < 4; ++i) {
      x2[i]     = xa[i] + (float)hv[i]     + (float)av[i];
      x2[4 + i] = xb[i] + (float)hv[4 + i] + (float)av[4 + i];
    }
    float s = 0.f, s2 = 0.f;
#pragma unroll
    for (int i = 0; i < 8; ++i) { s += x2[i]; s2 += x2[i] * x2[i]; }
    for (int off = 32; off; off >>= 1) { s += __shfl_xor(s, off); s2 += __shfl_xor(s2, off); }
    const float mean = s * (1.f / CC);
    const float var  = fmaxf(s2 * (1.f / CC) - mean * mean, 0.f);
    const float rstd = rsqrtf(var + 1e-5f);
    bf16x8 ox, om;
#pragma unroll
    for (int i = 0; i < 4; ++i) {
      ox[i]     = (bf16_t)x2[i];
      ox[4 + i] = (bf16_t)x2[4 + i];
      om[i]     = (bf16_t)(w0[i] * (x2[i] - mean) * rstd + bb0[i]);
      om[4 + i] = (bf16_t)(w1[i] * (x2[4 + i] - mean) * rstd + bb1[i]);
    }
    *(bf16x8*)(x2b + tok * CC + c0) = ox;
    *(bf16x8*)(mout + tok * CC + c0) = om;
    xa = xa1; xb = xb1; hv = hv1;
  }
}

// ---- 8-phase GEMM (r6 schedule) with 32x32x16 MFMA ----
// Swizzle enriched: swz(row) = ((row>>1)&3) ^ ((row>>3)&3), applied to staging
// source col and fragment reads (lane-only for reads; bases are 32-multiples).
// GELU=false epilogue: pure store out = x2b + acc + bias (no fp32 RMW read).
template <int K, int NOUT, int BN, bool GELU>
__global__ __launch_bounds__(512, 2) void gemm8p_kernel(const bf16_t* __restrict__ A,
                                                        const bf16_t* __restrict__ Bw,
                                                        const float* __restrict__ bias,
                                                        bf16_t* __restrict__ outb,
                                                        float* __restrict__ outf,
                                                        const bf16_t* __restrict__ x2b) {
  constexpr int NTILE = NOUT / BN;
  constexpr int NT = K / 64;                 // K-tiles
  constexpr int NI = NT / 2;                 // iterations (2 K-tiles each)
  constexpr int WNSPAN = BN / 4;             // wave N span (64 or 32)
  constexpr int NF2 = WNSPAN / 32;           // 32-wide N frags per wave (2 or 1)
  constexpr int BLOADS = BN / 128;           // B loads per ks-unit (2 or 1)
  constexpr int ABYT = 32768;                // A bytes per buffer
  constexpr int BBYT = BN * 128;             // B bytes per buffer
  constexpr int BUFB = ABYT + BBYT;
  constexpr int KSB = BN * 64;               // B kslice stride (bytes)

  __shared__ char lds[2 * BUFB];

  const int tid = threadIdx.x;
  const int wid = tid >> 6, lane = tid & 63;
  const int wm = wid >> 2, wn = wid & 3;
  const int l31 = lane & 31, kg5 = lane >> 5;

  int bid = blockIdx.x;
  const int qq = gridDim.x >> 3;
  bid = (bid & 7) * qq + (bid >> 3);        // XCD swizzle (grid % 8 == 0)
  const long row0 = (long)(bid / NTILE) * 256;
  const long col0 = (long)(bid % NTILE) * BN;

  const int srow = tid >> 2;                                   // 0..127
  const int ssw = (((srow >> 1) & 3) ^ ((srow >> 3) & 3));     // enriched swizzle
  const int sce = (((tid & 3) ^ ssw) << 3);                    // pre-swizzled col
  const bf16_t* pA = A + (row0 + srow) * (long)K + sce;
  const bf16_t* pB = Bw + (col0 + srow) * (long)K + sce;
  char* ldsp = (char*)lds;

  auto SA = [&](int buf, int ks, int kt) {
    char* d_ = ldsp + buf * BUFB + ks * 16384 + tid * 16;
    const bf16_t* g_ = pA + (long)kt * 64 + ks * 32;
    gload_lds16(g_, d_);
    gload_lds16(g_ + 128L * K, d_ + 8192);
  };
  auto SB = [&](int buf, int ks, int kt) {
    char* d_ = ldsp + buf * BUFB + ABYT + ks * KSB + tid * 16;
    const bf16_t* g_ = pB + (long)kt * 64 + ks * 32;
    gload_lds16(g_, d_);
    if constexpr (BLOADS == 2) gload_lds16(g_ + 128L * K, d_ + 8192);
  };

  f32x16 acc[4][NF2] = {};
  bf16x8 af[4], bf[NF2];

  // fragment-read bases. swz = ((l31>>1)&3)^((l31>>3)&3) is lane-only
  // (mf*32/nf*32 bases keep row bits 1-4); chunk (k16<<1|kg5) -> stored ^swz.
  const int swz = ((l31 >> 1) & 3) ^ ((l31 >> 3) & 3);
  const int cb0 = (((0 << 1) | kg5) ^ swz) << 4;
  const int cb1 = (((1 << 1) | kg5) ^ swz) << 4;
  const char* aR = ldsp + (wm * 128 + l31) * 64;
  const char* bR = ldsp + ABYT + (wn * WNSPAN + l31) * 64;

  auto RD = [&](int buf, int ks, int k16) {
    const int cb = k16 ? cb1 : cb0;
    const char* a_ = aR + buf * BUFB + ks * 16384 + cb;
    const char* b_ = bR + buf * BUFB + ks * KSB + cb;
#pragma unroll
    for (int mf = 0; mf < 4; ++mf) af[mf] = *(const bf16x8*)(a_ + mf * 2048);
#pragma unroll
    for (int nf = 0; nf < NF2; ++nf) bf[nf] = *(const bf16x8*)(b_ + nf * 2048);
  };
  auto MM = [&]() {
    __builtin_amdgcn_s_setprio(1);
#pragma unroll
    for (int mf = 0; mf < 4; ++mf)
#pragma unroll
      for (int nf = 0; nf < NF2; ++nf)
        acc[mf][nf] =
            __builtin_amdgcn_mfma_f32_32x32x16_bf16(af[mf], bf[nf], acc[mf][nf], 0, 0, 0);
    __builtin_amdgcn_s_setprio(0);
  };
  auto W2U = [&]() {
    if constexpr (BLOADS == 2) asm volatile("s_waitcnt vmcnt(8)" ::: "memory");
    else                       asm volatile("s_waitcnt vmcnt(6)" ::: "memory");
  };
  auto W1U = [&]() {
    if constexpr (BLOADS == 2) asm volatile("s_waitcnt vmcnt(4)" ::: "memory");
    else                       asm volatile("s_waitcnt vmcnt(3)" ::: "memory");
  };
#define BARX() __builtin_amdgcn_s_barrier()
#define LGKM0() asm volatile("s_waitcnt lgkmcnt(0)" ::: "memory")
#define W0U() asm volatile("s_waitcnt vmcnt(0)" ::: "memory")

  // prologue: stage 3 units in consumption order; land unit 1 only
  SA(0, 0, 0); SB(0, 0, 0);
  SA(0, 1, 0); SB(0, 1, 0);
  SA(1, 0, 1); SB(1, 0, 1);
  W2U();
  BARX();

  for (int i = 0; i < NI; ++i) {
    const int t1 = 2 * i + 1, tA = 2 * i + 2, tB = 2 * i + 3;
    // p1: read b0.ks0.k0 | stage b1k1.A
    RD(0, 0, 0); SA(1, 1, t1);
    BARX(); LGKM0(); MM(); BARX();
    // p2: read b0.ks0.k1 | stage b1k1.B | wait lands b0k1 (for p3/p4)
    RD(0, 0, 1); SB(1, 1, t1);
    BARX(); LGKM0(); MM(); W2U(); BARX();
    // p3: read b0.ks1.k0 | stage next b0k0.A
    RD(0, 1, 0); if (tA < NT) SA(0, 0, tA);
    BARX(); LGKM0(); MM(); BARX();
    // p4: read b0.ks1.k1 | stage next b0k0.B | wait lands b1k0 (for p5/p6)
    RD(0, 1, 1); if (tA < NT) SB(0, 0, tA);
    BARX(); LGKM0(); MM();
    if (tA < NT) W2U(); else W1U();
    BARX();
    // p5: read b1.ks0.k0 | stage next b0k1.A
    RD(1, 0, 0); if (tA < NT) SA(0, 1, tA);
    BARX(); LGKM0(); MM(); BARX();
    // p6: read b1.ks0.k1 | stage next b0k1.B | wait lands b1k1 (for p7/p8)
    RD(1, 0, 1); if (tA < NT) SB(0, 1, tA);
    BARX(); LGKM0(); MM();
    if (tA < NT) W2U(); else W0U();
    BARX();
    // p7: read b1.ks1.k0 | stage next b1k0.A
    RD(1, 1, 0); if (tB < NT) SA(1, 0, tB);
    BARX(); LGKM0(); MM(); BARX();
    // p8: read b1.ks1.k1 | stage next b1k0.B | wait lands next b0k0
    RD(1, 1, 1); if (tB < NT) SB(1, 0, tB);
    BARX(); LGKM0(); MM();
    if (tB < NT) W2U();
    BARX();
  }
#undef BARX
#undef LGKM0
#undef W0U

  // epilogue: 32x32 C/D layout: col = l31, row = (r&3) + 8*(r>>2) + 4*kg5
#pragma unroll
  for (int mf = 0; mf < 4; ++mf) {
#pragma unroll
    for (int nf = 0; nf < NF2; ++nf) {
      const long col = col0 + wn * WNSPAN + nf * 32 + l31;
      const float bs = bias[col];
#pragma unroll
      for (int r = 0; r < 16; ++r) {
        const long row = row0 + wm * 128 + mf * 32 + (r & 3) + 8 * (r >> 2) + 4 * kg5;
        const float v = acc[mf][nf][r] + bs;
        if constexpr (GELU) {
          const float u = 0.7978845608028654f * (v + 0.044715f * v * v * v);
          const float gv = v / (1.f + __expf(-2.f * u));
          outb[row * NOUT + col] = (bf16_t)gv;
        } else {
          // pure store: final out = x2 + mlp (x2 read back as bf16 from ws)
          outf[row * NOUT + col] = (float)x2b[row * NOUT + col] + v;
        }
      }
    }
  }
}

extern "C" void kernel_launch(void* const* d_in, const int* in_sizes, int n_in,
                              void* d_out, int out_size, void* d_ws, size_t ws_size,
                              hipStream_t stream) {
  const float* x   = (const float*)d_in[0];
  const float* n1w = (const float*)d_in[2];
  const float* n1b = (const float*)d_in[3];
  const float* klw = (const float*)d_in[4];
  const float* klb = (const float*)d_in[5];
  const float* vlw = (const float*)d_in[6];
  const float* vlb = (const float*)d_in[7];
  const float* n2w = (const float*)d_in[8];
  const float* n2b = (const float*)d_in[9];
  const float* w1f = (const float*)d_in[10];
  const float* b1  = (const float*)d_in[11];
  const float* w2f = (const float*)d_in[12];
  const float* b2  = (const float*)d_in[13];
  float* out = (float*)d_out;

  // nch=2: act chunk = 128MB -> L3-resident between GEMM1 and GEMM2
  int nch;
  if (ws_size >= 360000000ULL) nch = 2;
  else                         nch = 4;
  const long mch = MTOT / nch;

  char* ws = (char*)d_ws;
  size_t off = 0;
  bf16_t* h   = (bf16_t*)(ws + off); off += (size_t)MTOT * CC * 2;      // 64 MiB
  bf16_t* mb  = (bf16_t*)(ws + off); off += (size_t)MTOT * CC * 2;      // 64 MiB
  bf16_t* x2b = (bf16_t*)(ws + off); off += (size_t)MTOT * CC * 2;      // 64 MiB
  bf16_t* act = (bf16_t*)(ws + off); off += (size_t)mch * HID * 2;      // 256/nch MiB
  bf16_t* w1  = (bf16_t*)(ws + off); off += (size_t)HID * CC * 2;       // 2 MiB
  bf16_t* w2  = (bf16_t*)(ws + off); off += (size_t)HID * CC * 2;       // 2 MiB
  float*  kvp = (float*)(ws + off);  off += (size_t)BB * HH * 64 * 1024 * 4; // 16 MiB
  bf16_t* kvT = (bf16_t*)(ws + off);                                    // 128 KiB

  cvt_bf16_kernel<<<1024, 256, 0, stream>>>(w1f, w1);
  cvt_bf16_kernel<<<1024, 256, 0, stream>>>(w2f, w2);
  norm1_kernel<<<MTOT / 4, 256, 0, stream>>>(x, n1w, n1b, h);
  kv_partial_kernel<<<BB * HH * 64, 256, 0, stream>>>(h, klw, klb, vlw, vlb, kvp);
  kv_reduce_kernel<<<BB * HH, 256, 0, stream>>>(kvp, kvT);
  attn_fused_kernel<<<MTOT / 32, 256, 0, stream>>>(x, h, kvT, n2w, n2b, x2b, mb);
  for (int ch = 0; ch < nch; ++ch) {
    gemm8p_kernel<CC, HID, 256, true>
        <<<(int)((mch / 256) * (HID / 256)), 512, 0, stream>>>(
        mb + (size_t)ch * mch * CC, w1, b1, act, nullptr, nullptr);
    if (mch >= 32768) {
      gemm8p_kernel<HID, CC, 256, false>
          <<<(int)((mch / 256) * (CC / 256)), 512, 0, stream>>>(
          act, w2, b2, nullptr, out + (size_t)ch * mch * CC,
          x2b + (size_t)ch * mch * CC);
    } else {
      gemm8p_kernel<HID, CC, 128, false>
          <<<(int)((mch / 256) * (CC / 128)), 512, 0, stream>>>(
          act, w2, b2, nullptr, out + (size_t)ch * mch * CC,
          x2b + (size_t)ch * mch * CC);
    }
  }
}